// Round 2
// baseline (1334.529 us; speedup 1.0000x reference)
//
#include <hip/hip_runtime.h>

constexpr int FD   = 128;
constexpr int NMAX = 50000;
constexpr int EDG  = 800000;

static __device__ __forceinline__ unsigned enc(float f){
  unsigned u = __float_as_uint(f);
  return (u & 0x80000000u) ? ~u : (u | 0x80000000u);
}
static __device__ __forceinline__ float dec(unsigned e){
  unsigned u = (e & 0x80000000u) ? (e ^ 0x80000000u) : ~e;
  return __uint_as_float(u);
}

// ---------------- CSR build ----------------
__global__ void k_count(const int* __restrict__ src, const int* __restrict__ dst,
                        int* __restrict__ deg, int E){
  int e = blockIdx.x*256 + threadIdx.x;
  if (e >= E) return;
  int s = src[e], d = dst[e];
  if (s != d) atomicAdd(&deg[d], 1);
}

__global__ void k_remap_count(const int* __restrict__ sIn, const int* __restrict__ dIn,
                              int* __restrict__ sOut, int* __restrict__ dOut,
                              const int* __restrict__ rank, int kNew,
                              int* __restrict__ deg, int E){
  int e = blockIdx.x*256 + threadIdx.x;
  if (e >= E) return;
  int s = sIn[e], d = dIn[e];
  int rs = rank[s], rd = rank[d];
  bool ok = (rs >= 0) && (rd >= 0);
  int os = ok ? rs : kNew, od = ok ? rd : kNew;
  sOut[e] = os; dOut[e] = od;
  if (os != od) atomicAdd(&deg[od], 1);
}

__global__ void k_scan(int* __restrict__ off, int* __restrict__ cur, int n){
  __shared__ int wsum[16];
  __shared__ int carry;
  int tid = threadIdx.x, lane = tid & 63, wid = tid >> 6;
  if (tid == 0) carry = 0;
  __syncthreads();
  for (int base = 0; base < n; base += 1024){
    int v = base + tid;
    int x = (v < n) ? off[v] : 0;
    int val = x;
    #pragma unroll
    for (int o = 1; o < 64; o <<= 1){ int t = __shfl_up(val, o); if (lane >= o) val += t; }
    if (lane == 63) wsum[wid] = val;
    __syncthreads();
    if (tid < 16){
      int v2 = wsum[tid];
      #pragma unroll
      for (int o = 1; o < 16; o <<= 1){ int t = __shfl_up(v2, o); if (tid >= o) v2 += t; }
      wsum[tid] = v2;
    }
    __syncthreads();
    int add = (wid > 0) ? wsum[wid-1] : 0;
    int incl = val + add;
    int c0 = carry;
    if (v < n){ int e0 = c0 + incl - x; off[v] = e0; cur[v] = e0; }
    __syncthreads();
    if (tid == 0) carry = c0 + wsum[15];
    __syncthreads();
  }
  if (tid == 0) off[n] = carry;
}

__global__ void k_fill(const int* __restrict__ src, const int* __restrict__ dst,
                       int* __restrict__ cur, int* __restrict__ csr, int E){
  int e = blockIdx.x*256 + threadIdx.x;
  if (e >= E) return;
  int s = src[e], d = dst[e];
  if (s != d){ int pos = atomicAdd(&cur[d], 1); csr[pos] = s; }
}

// ---------------- aggregation: agg = (sum_nb x + x) / (deg+1) ----------------
__global__ __launch_bounds__(256) void k_agg(const float* __restrict__ X,
    const int* __restrict__ off, const int* __restrict__ csr,
    float* __restrict__ AGG, int n,
    float* __restrict__ zstats, unsigned* __restrict__ zmax){
  int tid = threadIdx.x;
  if (blockIdx.x == 0){
    zstats[tid & 255] = 0.f;          // 256 threads zero 256 floats
    if (zmax && tid < FD) zmax[tid] = 0u;
  }
  int v = blockIdx.x*4 + (tid >> 6);
  int c = (tid & 63) * 2;
  if (v >= n) return;
  int b = off[v], e = off[v+1];
  float2 s = *(const float2*)(X + (size_t)v*FD + c);
  for (int j = b; j < e; j++){
    int u = csr[j];
    float2 t = *(const float2*)(X + (size_t)u*FD + c);
    s.x += t.x; s.y += t.y;
  }
  float inv = 1.f / (float)(e - b + 1);
  float2 o; o.x = s.x*inv; o.y = s.y*inv;
  *(float2*)(AGG + (size_t)v*FD + c) = o;
}

// ---------------- GEMM + bias + L2norm + ReLU + BN-stats ----------------
__global__ __launch_bounds__(256,2) void k_gemm(const float* __restrict__ A,
    const float* __restrict__ W, const float* __restrict__ bias,
    float* __restrict__ Y, float* __restrict__ stats, int n){
  __shared__ float sW[FD*FD];
  __shared__ float ss[4][FD];
  __shared__ float sq_[4][FD];
  int tid = threadIdx.x;
  {
    const float4* Wg = (const float4*)W; float4* Ws = (float4*)sW;
    for (int i = tid; i < FD*FD/4; i += 256) Ws[i] = Wg[i];
  }
  __syncthreads();
  int tc = tid & 15;          // 16 col-groups * 8 cols
  int tr = tid >> 4;          // 16 row-groups * 8 rows
  int rbase = blockIdx.x*FD + tr*8;
  float acc[8][8];
  #pragma unroll
  for (int i = 0; i < 8; i++)
    #pragma unroll
    for (int j = 0; j < 8; j++) acc[i][j] = 0.f;

  for (int k4 = 0; k4 < FD; k4 += 4){
    float4 a[8];
    #pragma unroll
    for (int i = 0; i < 8; i++){
      int r = rbase + i; if (r >= n) r = n - 1;
      a[i] = *(const float4*)(A + (size_t)r*FD + k4);
    }
    #pragma unroll
    for (int kk = 0; kk < 4; kk++){
      const float* wr = &sW[(k4+kk)*FD + tc*8];
      float4 w0 = *(const float4*)wr, w1 = *(const float4*)(wr+4);
      #pragma unroll
      for (int i = 0; i < 8; i++){
        float av = (kk==0) ? a[i].x : (kk==1) ? a[i].y : (kk==2) ? a[i].z : a[i].w;
        acc[i][0] += av*w0.x; acc[i][1] += av*w0.y; acc[i][2] += av*w0.z; acc[i][3] += av*w0.w;
        acc[i][4] += av*w1.x; acc[i][5] += av*w1.y; acc[i][6] += av*w1.z; acc[i][7] += av*w1.w;
      }
    }
  }
  float bx[8];
  {
    const float* bp = bias + tc*8;
    #pragma unroll
    for (int j = 0; j < 8; j++) bx[j] = bp[j];
  }
  float cs[8], cq[8];
  #pragma unroll
  for (int j = 0; j < 8; j++){ cs[j]=0.f; cq[j]=0.f; }
  #pragma unroll
  for (int i = 0; i < 8; i++){
    int r = rbase + i;
    bool valid = (r < n);
    float y[8]; float sq = 0.f;
    #pragma unroll
    for (int j = 0; j < 8; j++){ y[j] = acc[i][j] + bx[j]; sq += y[j]*y[j]; }
    sq += __shfl_xor(sq,1); sq += __shfl_xor(sq,2); sq += __shfl_xor(sq,4); sq += __shfl_xor(sq,8);
    float nrm = sqrtf(sq);
    float sc = 1.f / fmaxf(nrm, 1e-12f);
    #pragma unroll
    for (int j = 0; j < 8; j++){ y[j] *= sc; y[j] = fmaxf(y[j], 0.f); }
    if (valid){
      float* yo = Y + (size_t)r*FD + tc*8;
      *(float4*)yo     = make_float4(y[0],y[1],y[2],y[3]);
      *(float4*)(yo+4) = make_float4(y[4],y[5],y[6],y[7]);
      #pragma unroll
      for (int j = 0; j < 8; j++){ cs[j] += y[j]; cq[j] += y[j]*y[j]; }
    }
  }
  #pragma unroll
  for (int j = 0; j < 8; j++){
    cs[j] += __shfl_xor(cs[j],16); cs[j] += __shfl_xor(cs[j],32);
    cq[j] += __shfl_xor(cq[j],16); cq[j] += __shfl_xor(cq[j],32);
  }
  int wv = tid >> 6, lane = tid & 63;
  if (lane < 16){
    #pragma unroll
    for (int j = 0; j < 8; j++){ ss[wv][tc*8+j] = cs[j]; sq_[wv][tc*8+j] = cq[j]; }
  }
  __syncthreads();
  if (tid < FD){
    float s_ = ss[0][tid]+ss[1][tid]+ss[2][tid]+ss[3][tid];
    float q_ = sq_[0][tid]+sq_[1][tid]+sq_[2][tid]+sq_[3][tid];
    atomicAdd(&stats[tid], s_);
    atomicAdd(&stats[FD+tid], q_);
  }
}

// ---------------- BN apply (in place) + optional column max ----------------
__global__ __launch_bounds__(256) void k_bn(float* __restrict__ X,
    const float* __restrict__ stats, const float* __restrict__ g,
    const float* __restrict__ b, int n, float invn, unsigned* __restrict__ cmax){
  int tid = threadIdx.x;
  int c = (tid & 63) * 2;
  int rh = tid >> 6;
  float ma = stats[c]*invn,    mb = stats[c+1]*invn;
  float va = stats[FD+c]*invn - ma*ma, vb = stats[FD+c+1]*invn - mb*mb;
  float ia = rsqrtf(va + 1e-5f), ib = rsqrtf(vb + 1e-5f);
  float ga = g[c]*ia, gb = g[c+1]*ib;
  float ba = b[c] - ma*ga, bb = b[c+1] - mb*gb;
  int r0 = blockIdx.x*16 + rh;
  float mxa = -1e38f, mxb = -1e38f;
  #pragma unroll
  for (int rr = 0; rr < 4; rr++){
    int r = r0 + rr*4;
    if (r < n){
      float2* p = (float2*)(X + (size_t)r*FD + c);
      float2 t = *p;
      t.x = t.x*ga + ba; t.y = t.y*gb + bb;
      *p = t;
      mxa = fmaxf(mxa, t.x); mxb = fmaxf(mxb, t.y);
    }
  }
  if (cmax){
    __shared__ float sm[4][FD];
    sm[rh][c] = mxa; sm[rh][c+1] = mxb;
    __syncthreads();
    if (tid < FD){
      float m = fmaxf(fmaxf(sm[0][tid],sm[1][tid]), fmaxf(sm[2][tid],sm[3][tid]));
      atomicMax(&cmax[tid], enc(m));
    }
  }
}

// ---------------- pool: p[v] = x[v] . wp ----------------
__global__ __launch_bounds__(256) void k_dotp(const float* __restrict__ X,
    const float* __restrict__ wp, float* __restrict__ p, int n){
  int tid = threadIdx.x;
  int v = blockIdx.x*4 + (tid >> 6), lane = tid & 63;
  if (v >= n) return;
  float2 x = *(const float2*)(X + (size_t)v*FD + lane*2);
  float2 w = *(const float2*)(wp + lane*2);
  float s = x.x*w.x + x.y*w.y;
  s += __shfl_xor(s,1); s += __shfl_xor(s,2); s += __shfl_xor(s,4);
  s += __shfl_xor(s,8); s += __shfl_xor(s,16); s += __shfl_xor(s,32);
  if (lane == 0) p[v] = s;
}

__global__ void k_score(const float* __restrict__ p, const int* __restrict__ off,
    const int* __restrict__ csr, const float* __restrict__ bpool, int pi,
    float* __restrict__ score, int n){
  int v = blockIdx.x*256 + threadIdx.x;
  if (v >= n) return;
  int b = off[v], e = off[v+1];
  float s = p[v];
  for (int j = b; j < e; j++) s += p[csr[j]];
  score[v] = tanhf(s / (float)(e - b + 1) + bpool[pi]);
}

// ---------------- exact top-k threshold via 4-pass radix select ----------------
__global__ void k_select(const float* __restrict__ score, int n, int k,
                         unsigned* __restrict__ state){
  __shared__ unsigned hist[256];
  __shared__ unsigned spfx, swant, sabove;
  int tid = threadIdx.x;
  if (tid == 0){ spfx = 0u; swant = (unsigned)k; sabove = 0u; }
  __syncthreads();
  for (int pass = 0; pass < 4; pass++){
    int sh = 24 - pass*8;
    unsigned mh = (pass == 0) ? 0u : (0xFFFFFFFFu << (sh + 8));
    if (tid < 256) hist[tid] = 0u;
    __syncthreads();
    unsigned pfx = spfx;
    for (int v = tid; v < n; v += 1024){
      unsigned key = enc(score[v]);
      if ((key & mh) == pfx) atomicAdd(&hist[(key >> sh) & 255u], 1u);
    }
    __syncthreads();
    if (tid == 0){
      unsigned cum = 0, above = 0; int bsel = 0;
      for (int bb = 255; bb >= 0; bb--){
        unsigned cc = hist[bb];
        if (cum + cc >= swant){ bsel = bb; above = cum; break; }
        cum += cc;
      }
      sabove += above;
      swant  -= above;
      spfx = pfx | ((unsigned)bsel << sh);
    }
    __syncthreads();
  }
  if (tid == 0){
    state[0] = spfx;    // T = k-th largest key
    state[1] = sabove;  // G = count(key > T)
    state[2] = 0u;      // slot counter for key > T
    state[3] = sabove;  // slot counter for ties (starts at G)
  }
}

__global__ void k_compact(const float* __restrict__ score, unsigned* __restrict__ state,
    int* __restrict__ rank, int* __restrict__ sel, int n, int k){
  int v = blockIdx.x*256 + threadIdx.x;
  if (v > n) return;
  if (v == n){ rank[n] = -1; return; }
  unsigned T = state[0];
  unsigned key = enc(score[v]);
  int slot = -1;
  if (key > T) slot = (int)atomicAdd(&state[2], 1u);
  else if (key == T){ unsigned t = atomicAdd(&state[3], 1u); if (t < (unsigned)k) slot = (int)t; }
  rank[v] = slot;
  if (slot >= 0) sel[slot] = v;
}

__global__ __launch_bounds__(256) void k_gather(const float* __restrict__ X,
    const int* __restrict__ sel, const float* __restrict__ score,
    float* __restrict__ XO, int k){
  int j = blockIdx.x*4 + (threadIdx.x >> 6), lane = threadIdx.x & 63;
  if (j >= k) return;
  int u = sel[j];
  float sc = score[u];
  float2 t = *(const float2*)(X + (size_t)u*FD + lane*2);
  t.x *= sc; t.y *= sc;
  *(float2*)(XO + (size_t)j*FD + lane*2) = t;
}

// ---------------- final MLP ----------------
__global__ void k_final(const unsigned* __restrict__ cmax, const float* __restrict__ W1,
    const float* __restrict__ b1, const float* __restrict__ W2,
    const float* __restrict__ b2, float* __restrict__ out){
  __shared__ float h[384];
  __shared__ float h1[50];
  int tid = threadIdx.x;
  if (tid < 384) h[tid] = dec(cmax[tid]);
  __syncthreads();
  if (tid < 50){
    float a = b1[tid];
    for (int i = 0; i < 384; i++) a += h[i]*W1[i*50 + tid];
    h1[tid] = fmaxf(a, 0.f);
  }
  __syncthreads();
  if (tid < 5){
    float a = b2[tid];
    for (int i = 0; i < 50; i++) a += h1[i]*W2[i*5 + tid];
    out[tid] = a;
  }
}

extern "C" void kernel_launch(void* const* d_in, const int* in_sizes, int n_in,
                              void* d_out, int out_size, void* d_ws, size_t ws_size,
                              hipStream_t stream){
  (void)in_sizes; (void)n_in; (void)out_size; (void)ws_size;
  const float* x_in  = (const float*)d_in[0];
  const int*   ei    = (const int*)d_in[1];       // [2][E]
  const float* Wc    = (const float*)d_in[2];     // [9][128][128]
  const float* bc    = (const float*)d_in[3];     // [9][128]
  const float* gamma = (const float*)d_in[4];
  const float* beta  = (const float*)d_in[5];
  const float* Wpool = (const float*)d_in[6];     // [2][128]
  const float* bpool = (const float*)d_in[7];     // [2]
  const float* W1    = (const float*)d_in[8];
  const float* b1    = (const float*)d_in[9];
  const float* W2    = (const float*)d_in[10];
  const float* b2    = (const float*)d_in[11];
  float* dout = (float*)d_out;

  char* base = (char*)d_ws; size_t o_ = 0;
  auto alloc = [&](size_t bytes)->void*{
    void* p = base + o_; o_ = (o_ + bytes + 255) & ~(size_t)255; return p;
  };
  float* B0   = (float*)alloc((size_t)NMAX*FD*4);
  float* B1   = (float*)alloc((size_t)NMAX*FD*4);
  int* eSrc   = (int*)alloc((size_t)EDG*4);
  int* eDst   = (int*)alloc((size_t)EDG*4);
  int* offv   = (int*)alloc((size_t)(NMAX+1)*4);
  int* cur    = (int*)alloc((size_t)NMAX*4);
  int* csr    = (int*)alloc((size_t)EDG*4);
  float* pbuf = (float*)alloc((size_t)NMAX*4);
  float* sbuf = (float*)alloc((size_t)NMAX*4);
  int* sel    = (int*)alloc((size_t)25000*4);
  int* rank   = (int*)alloc((size_t)(NMAX+1)*4);
  float* stats= (float*)alloc(256*4);
  unsigned* cmax = (unsigned*)alloc(384*4);
  unsigned* state= (unsigned*)alloc(64);

  const int ns[3]  = {50000, 25000, 12500};
  const int bnIdx[9] = {0,1,2,3,4,5,6,6,8};   // replicate the source bug (6,6,8)
  const int EB = (EDG + 255)/256;

  const int* cs = ei;
  const int* cd = ei + EDG;

  for (int s = 0; s < 3; s++){
    int n = ns[s];
    float* X = (s == 1) ? B1 : B0;
    float* A = (s == 1) ? B0 : B1;

    // ---- CSR build (reused by 3 convs + pool score) ----
    hipMemsetAsync(offv, 0, (size_t)(n+1)*4, stream);
    if (s == 0){
      k_count<<<dim3(EB), dim3(256), 0, stream>>>(cs, cd, offv, EDG);
    } else {
      k_remap_count<<<dim3(EB), dim3(256), 0, stream>>>(cs, cd, eSrc, eDst, rank, n, offv, EDG);
      cs = eSrc; cd = eDst;
    }
    k_scan<<<1, 1024, 0, stream>>>(offv, cur, n);
    k_fill<<<dim3(EB), dim3(256), 0, stream>>>(cs, cd, cur, csr, EDG);

    for (int i = 0; i < 3; i++){
      int li = s*3 + i;
      const float* xr = (s == 0 && i == 0) ? x_in : (const float*)X;
      unsigned* cm = (i == 2) ? (cmax + s*FD) : (unsigned*)nullptr;
      k_agg<<<dim3((n+3)/4), dim3(256), 0, stream>>>(xr, offv, csr, A, n, stats, cm);
      k_gemm<<<dim3((n+FD-1)/FD), dim3(256), 0, stream>>>(A, Wc + (size_t)li*FD*FD, bc + li*FD, X, stats, n);
      k_bn<<<dim3((n+15)/16), dim3(256), 0, stream>>>(X, stats, gamma + bnIdx[li]*FD, beta + bnIdx[li]*FD,
                                                      n, 1.f/(float)n, cm);
    }

    if (s < 2){
      int k = (s == 0) ? 25000 : 12500;
      k_dotp<<<dim3((n+3)/4), dim3(256), 0, stream>>>(X, Wpool + s*FD, pbuf, n);
      k_score<<<dim3((n+255)/256), dim3(256), 0, stream>>>(pbuf, offv, csr, bpool, s, sbuf, n);
      k_select<<<1, 1024, 0, stream>>>(sbuf, n, k, state);
      k_compact<<<dim3((n+256)/256), dim3(256), 0, stream>>>(sbuf, state, rank, sel, n, k);
      k_gather<<<dim3((k+3)/4), dim3(256), 0, stream>>>(X, sel, sbuf, A, k);
      // A now holds the pooled x and becomes next stage's X (ping-pong).
    }
  }
  k_final<<<1, 384, 0, stream>>>(cmax, W1, b1, W2, b2, dout);
}

// Round 5
// 1164.649 us; speedup vs baseline: 1.1459x; 1.1459x over previous
//
#include <hip/hip_runtime.h>

constexpr int FD   = 128;
constexpr int NMAX = 50000;
constexpr int EDG  = 800000;

static __device__ __forceinline__ unsigned enc(float f){
  unsigned u = __float_as_uint(f);
  return (u & 0x80000000u) ? ~u : (u | 0x80000000u);
}
static __device__ __forceinline__ float dec(unsigned e){
  unsigned u = (e & 0x80000000u) ? (e ^ 0x80000000u) : ~e;
  return __uint_as_float(u);
}

// ---------------- CSR build ----------------
__global__ void k_count(const int* __restrict__ src, const int* __restrict__ dst,
                        int* __restrict__ deg, int E){
  int e = blockIdx.x*256 + threadIdx.x;
  if (e >= E) return;
  int s = src[e], d = dst[e];
  if (s != d) atomicAdd(&deg[d], 1);
}

__global__ void k_remap_count(const int* __restrict__ sIn, const int* __restrict__ dIn,
                              int* __restrict__ sOut, int* __restrict__ dOut,
                              const int* __restrict__ rank, int kNew,
                              int* __restrict__ deg, int E){
  int e = blockIdx.x*256 + threadIdx.x;
  if (e >= E) return;
  int s = sIn[e], d = dIn[e];
  int rs = rank[s], rd = rank[d];
  bool ok = (rs >= 0) && (rd >= 0);
  int os = ok ? rs : kNew, od = ok ? rd : kNew;
  sOut[e] = os; dOut[e] = od;
  if (os != od) atomicAdd(&deg[od], 1);
}

__global__ void k_scan(int* __restrict__ off, int* __restrict__ cur, int n){
  __shared__ int wsum[16];
  __shared__ int carry;
  int tid = threadIdx.x, lane = tid & 63, wid = tid >> 6;
  if (tid == 0) carry = 0;
  __syncthreads();
  for (int base = 0; base < n; base += 1024){
    int v = base + tid;
    int x = (v < n) ? off[v] : 0;
    int val = x;
    #pragma unroll
    for (int o = 1; o < 64; o <<= 1){ int t = __shfl_up(val, o); if (lane >= o) val += t; }
    if (lane == 63) wsum[wid] = val;
    __syncthreads();
    if (tid < 16){
      int v2 = wsum[tid];
      #pragma unroll
      for (int o = 1; o < 16; o <<= 1){ int t = __shfl_up(v2, o); if (tid >= o) v2 += t; }
      wsum[tid] = v2;
    }
    __syncthreads();
    int add = (wid > 0) ? wsum[wid-1] : 0;
    int incl = val + add;
    int c0 = carry;
    if (v < n){ int e0 = c0 + incl - x; off[v] = e0; cur[v] = e0; }
    __syncthreads();
    if (tid == 0) carry = c0 + wsum[15];
    __syncthreads();
  }
  if (tid == 0) off[n] = carry;
}

__global__ void k_fill(const int* __restrict__ src, const int* __restrict__ dst,
                       int* __restrict__ cur, int* __restrict__ csr, int E){
  int e = blockIdx.x*256 + threadIdx.x;
  if (e >= E) return;
  int s = src[e], d = dst[e];
  if (s != d){ int pos = atomicAdd(&cur[d], 1); csr[pos] = s; }
}

// -------- aggregation: agg = (sum_nb x + x)/(deg+1); lane-coop index fetch + 4-way MLP --------
__global__ __launch_bounds__(256) void k_agg(const float* __restrict__ X,
    const int* __restrict__ off, const int* __restrict__ csr,
    float* __restrict__ AGG, int n,
    float* __restrict__ zstats, unsigned* __restrict__ zmax){
  int tid = threadIdx.x;
  if (blockIdx.x == 0){
    zstats[tid & 255] = 0.f;
    if (zmax && tid < FD) zmax[tid] = 0u;
  }
  int v = blockIdx.x*4 + (tid >> 6);
  if (v >= n) return;
  int lane = tid & 63;
  int c = lane * 2;
  int b = off[v], e = off[v+1];
  int deg = e - b;
  float2 s = *(const float2*)(X + (size_t)v*FD + c);
  int j = 0;
  while (j < deg){
    int cnt = deg - j; if (cnt > 64) cnt = 64;
    int myu = (j + lane < deg) ? csr[b + j + lane] : 0;
    int t = 0;
    for (; t + 4 <= cnt; t += 4){
      int u0 = __shfl(myu, t);
      int u1 = __shfl(myu, t+1);
      int u2 = __shfl(myu, t+2);
      int u3 = __shfl(myu, t+3);
      float2 t0 = *(const float2*)(X + (size_t)u0*FD + c);
      float2 t1 = *(const float2*)(X + (size_t)u1*FD + c);
      float2 t2 = *(const float2*)(X + (size_t)u2*FD + c);
      float2 t3 = *(const float2*)(X + (size_t)u3*FD + c);
      s.x += t0.x + t1.x + t2.x + t3.x;
      s.y += t0.y + t1.y + t2.y + t3.y;
    }
    for (; t < cnt; t++){
      int u = __shfl(myu, t);
      float2 tt = *(const float2*)(X + (size_t)u*FD + c);
      s.x += tt.x; s.y += tt.y;
    }
    j += cnt;
  }
  float inv = 1.f / (float)(deg + 1);
  float2 o; o.x = s.x*inv; o.y = s.y*inv;
  *(float2*)(AGG + (size_t)v*FD + c) = o;
}

// ---------------- GEMM + bias + L2norm + ReLU + BN-stats ----------------
__global__ __launch_bounds__(256,2) void k_gemm(const float* __restrict__ A,
    const float* __restrict__ W, const float* __restrict__ bias,
    float* __restrict__ Y, float* __restrict__ stats, int n){
  __shared__ float sW[FD*FD];
  __shared__ float ss[4][FD];
  __shared__ float sq_[4][FD];
  int tid = threadIdx.x;
  {
    const float4* Wg = (const float4*)W; float4* Ws = (float4*)sW;
    for (int i = tid; i < FD*FD/4; i += 256) Ws[i] = Wg[i];
  }
  __syncthreads();
  int tc = tid & 15;
  int tr = tid >> 4;
  int rbase = blockIdx.x*FD + tr*8;
  float acc[8][8];
  #pragma unroll
  for (int i = 0; i < 8; i++)
    #pragma unroll
    for (int j = 0; j < 8; j++) acc[i][j] = 0.f;

  for (int k4 = 0; k4 < FD; k4 += 4){
    float4 a[8];
    #pragma unroll
    for (int i = 0; i < 8; i++){
      int r = rbase + i; if (r >= n) r = n - 1;
      a[i] = *(const float4*)(A + (size_t)r*FD + k4);
    }
    #pragma unroll
    for (int kk = 0; kk < 4; kk++){
      const float* wr = &sW[(k4+kk)*FD + tc*8];
      float4 w0 = *(const float4*)wr, w1 = *(const float4*)(wr+4);
      #pragma unroll
      for (int i = 0; i < 8; i++){
        float av = (kk==0) ? a[i].x : (kk==1) ? a[i].y : (kk==2) ? a[i].z : a[i].w;
        acc[i][0] += av*w0.x; acc[i][1] += av*w0.y; acc[i][2] += av*w0.z; acc[i][3] += av*w0.w;
        acc[i][4] += av*w1.x; acc[i][5] += av*w1.y; acc[i][6] += av*w1.z; acc[i][7] += av*w1.w;
      }
    }
  }
  float bx[8];
  {
    const float* bp = bias + tc*8;
    #pragma unroll
    for (int j = 0; j < 8; j++) bx[j] = bp[j];
  }
  float cs[8], cq[8];
  #pragma unroll
  for (int j = 0; j < 8; j++){ cs[j]=0.f; cq[j]=0.f; }
  #pragma unroll
  for (int i = 0; i < 8; i++){
    int r = rbase + i;
    bool valid = (r < n);
    float y[8]; float sq = 0.f;
    #pragma unroll
    for (int j = 0; j < 8; j++){ y[j] = acc[i][j] + bx[j]; sq += y[j]*y[j]; }
    sq += __shfl_xor(sq,1); sq += __shfl_xor(sq,2); sq += __shfl_xor(sq,4); sq += __shfl_xor(sq,8);
    float nrm = sqrtf(sq);
    float sc = 1.f / fmaxf(nrm, 1e-12f);
    #pragma unroll
    for (int j = 0; j < 8; j++){ y[j] *= sc; y[j] = fmaxf(y[j], 0.f); }
    if (valid){
      float* yo = Y + (size_t)r*FD + tc*8;
      *(float4*)yo     = make_float4(y[0],y[1],y[2],y[3]);
      *(float4*)(yo+4) = make_float4(y[4],y[5],y[6],y[7]);
      #pragma unroll
      for (int j = 0; j < 8; j++){ cs[j] += y[j]; cq[j] += y[j]*y[j]; }
    }
  }
  #pragma unroll
  for (int j = 0; j < 8; j++){
    cs[j] += __shfl_xor(cs[j],16); cs[j] += __shfl_xor(cs[j],32);
    cq[j] += __shfl_xor(cq[j],16); cq[j] += __shfl_xor(cq[j],32);
  }
  int wv = tid >> 6, lane = tid & 63;
  if (lane < 16){
    #pragma unroll
    for (int j = 0; j < 8; j++){ ss[wv][tc*8+j] = cs[j]; sq_[wv][tc*8+j] = cq[j]; }
  }
  __syncthreads();
  if (tid < FD){
    float s_ = ss[0][tid]+ss[1][tid]+ss[2][tid]+ss[3][tid];
    float q_ = sq_[0][tid]+sq_[1][tid]+sq_[2][tid]+sq_[3][tid];
    atomicAdd(&stats[tid], s_);
    atomicAdd(&stats[FD+tid], q_);
  }
}

// -------- BN apply (in place) + optional column max + optional fused pool dot --------
__global__ __launch_bounds__(256) void k_bn(float* __restrict__ X,
    const float* __restrict__ stats, const float* __restrict__ g,
    const float* __restrict__ b, int n, float invn, unsigned* __restrict__ cmax,
    const float* __restrict__ wp, float* __restrict__ p){
  int tid = threadIdx.x;
  int c = (tid & 63) * 2;
  int rh = tid >> 6;
  float ma = stats[c]*invn,    mb = stats[c+1]*invn;
  float va = stats[FD+c]*invn - ma*ma, vb = stats[FD+c+1]*invn - mb*mb;
  float ia = rsqrtf(va + 1e-5f), ib = rsqrtf(vb + 1e-5f);
  float ga = g[c]*ia, gb = g[c+1]*ib;
  float ba = b[c] - ma*ga, bb = b[c+1] - mb*gb;
  float wa = 0.f, wb = 0.f;
  if (wp){ wa = wp[c]; wb = wp[c+1]; }
  int r0 = blockIdx.x*16 + rh;
  float mxa = -1e38f, mxb = -1e38f;
  #pragma unroll
  for (int rr = 0; rr < 4; rr++){
    int r = r0 + rr*4;
    if (r < n){
      float2* pp = (float2*)(X + (size_t)r*FD + c);
      float2 t = *pp;
      t.x = t.x*ga + ba; t.y = t.y*gb + bb;
      *pp = t;
      mxa = fmaxf(mxa, t.x); mxb = fmaxf(mxb, t.y);
      if (wp){
        float d = t.x*wa + t.y*wb;
        d += __shfl_xor(d,1);  d += __shfl_xor(d,2);  d += __shfl_xor(d,4);
        d += __shfl_xor(d,8);  d += __shfl_xor(d,16); d += __shfl_xor(d,32);
        if ((tid & 63) == 0) p[r] = d;
      }
    }
  }
  if (cmax){
    __shared__ float sm[4][FD];
    sm[rh][c] = mxa; sm[rh][c+1] = mxb;
    __syncthreads();
    if (tid < FD){
      float m = fmaxf(fmaxf(sm[0][tid],sm[1][tid]), fmaxf(sm[2][tid],sm[3][tid]));
      atomicMax(&cmax[tid], enc(m));
    }
  }
}

__global__ void k_score(const float* __restrict__ p, const int* __restrict__ off,
    const int* __restrict__ csr, const float* __restrict__ bpool, int pi,
    float* __restrict__ score, int n){
  int v = blockIdx.x*256 + threadIdx.x;
  if (v >= n) return;
  int b = off[v], e = off[v+1];
  float s = p[v];
  for (int j = b; j < e; j++) s += p[csr[j]];
  score[v] = tanhf(s / (float)(e - b + 1) + bpool[pi]);
}

// -------- multi-block radix select (two 16-bit digits) --------
__global__ void k_hist_hi(const float* __restrict__ score, int n, unsigned* __restrict__ hist){
  int v = blockIdx.x*256 + threadIdx.x;
  if (v >= n) return;
  unsigned key = enc(score[v]);
  atomicAdd(&hist[key >> 16], 1u);
}

__global__ void k_hist_lo(const float* __restrict__ score, int n,
                          const unsigned* __restrict__ state, unsigned* __restrict__ hist){
  int v = blockIdx.x*256 + threadIdx.x;
  if (v >= n) return;
  unsigned key = enc(score[v]);
  if ((key >> 16) == state[5]) atomicAdd(&hist[key & 0xFFFFu], 1u);
}

// pick threshold digit from a 64K-bin histogram; pass 0 = high digit, pass 1 = low digit.
__global__ __launch_bounds__(1024) void k_pick(const unsigned* __restrict__ hist,
                                               unsigned* __restrict__ state, int k, int pass){
  __shared__ unsigned wsum[16];
  int tid = threadIdx.x;
  unsigned want = (pass == 0) ? (unsigned)k : state[4];
  unsigned prevAbove = (pass == 0) ? 0u : state[1];
  int chunk = 1023 - tid;                 // descending key order
  const unsigned* hbase = hist + chunk*64;
  unsigned csum = 0;
  #pragma unroll
  for (int j = 0; j < 64; j++) csum += hbase[j];
  unsigned val = csum;
  int lane = tid & 63, wid = tid >> 6;
  #pragma unroll
  for (int o = 1; o < 64; o <<= 1){ unsigned t = __shfl_up(val, o); if (lane >= o) val += t; }
  if (lane == 63) wsum[wid] = val;
  __syncthreads();
  if (tid < 16){
    unsigned v2 = wsum[tid];
    #pragma unroll
    for (int o = 1; o < 16; o <<= 1){ unsigned t = __shfl_up(v2, o); if (tid >= o) v2 += t; }
    wsum[tid] = v2;
  }
  __syncthreads();
  unsigned incl = val + ((wid > 0) ? wsum[wid-1] : 0u);
  unsigned excl = incl - csum;
  if (excl < want && incl >= want){
    unsigned cum = excl, above = 0; int bsel = 0;
    for (int j = 63; j >= 0; j--){
      unsigned cc = hbase[j];
      if (cum + cc >= want){ bsel = j; above = cum; break; }
      cum += cc;
    }
    unsigned bucket = (unsigned)(chunk*64 + bsel);
    if (pass == 0){
      state[5] = bucket;
      state[1] = prevAbove + above;
      state[4] = want - above;
    } else {
      unsigned T = (state[5] << 16) | bucket;
      unsigned totAbove = prevAbove + above;
      state[0] = T; state[1] = totAbove; state[2] = 0u; state[3] = totAbove;
    }
  }
}

__global__ void k_compact(const float* __restrict__ score, unsigned* __restrict__ state,
    int* __restrict__ rank, int* __restrict__ sel, int n, int k){
  int v = blockIdx.x*256 + threadIdx.x;
  if (v > n) return;
  if (v == n){ rank[n] = -1; return; }
  unsigned T = state[0];
  unsigned key = enc(score[v]);
  int slot = -1;
  if (key > T) slot = (int)atomicAdd(&state[2], 1u);
  else if (key == T){ unsigned t = atomicAdd(&state[3], 1u); if (t < (unsigned)k) slot = (int)t; }
  rank[v] = slot;
  if (slot >= 0) sel[slot] = v;
}

__global__ __launch_bounds__(256) void k_gather(const float* __restrict__ X,
    const int* __restrict__ sel, const float* __restrict__ score,
    float* __restrict__ XO, int k){
  int j = blockIdx.x*4 + (threadIdx.x >> 6), lane = threadIdx.x & 63;
  if (j >= k) return;
  int u = sel[j];
  float sc = score[u];
  float2 t = *(const float2*)(X + (size_t)u*FD + lane*2);
  t.x *= sc; t.y *= sc;
  *(float2*)(XO + (size_t)j*FD + lane*2) = t;
}

// ---------------- final MLP ----------------
__global__ void k_final(const unsigned* __restrict__ cmax, const float* __restrict__ W1,
    const float* __restrict__ b1, const float* __restrict__ W2,
    const float* __restrict__ b2, float* __restrict__ out){
  __shared__ float h[384];
  __shared__ float h1[50];
  int tid = threadIdx.x;
  if (tid < 384) h[tid] = dec(cmax[tid]);
  __syncthreads();
  if (tid < 50){
    float a = b1[tid];
    for (int i = 0; i < 384; i++) a += h[i]*W1[i*50 + tid];
    h1[tid] = fmaxf(a, 0.f);
  }
  __syncthreads();
  if (tid < 5){
    float a = b2[tid];
    for (int i = 0; i < 50; i++) a += h1[i]*W2[i*5 + tid];
    out[tid] = a;
  }
}

extern "C" void kernel_launch(void* const* d_in, const int* in_sizes, int n_in,
                              void* d_out, int out_size, void* d_ws, size_t ws_size,
                              hipStream_t stream){
  (void)in_sizes; (void)n_in; (void)out_size; (void)ws_size;
  const float* x_in  = (const float*)d_in[0];
  const int*   ei    = (const int*)d_in[1];
  const float* Wc    = (const float*)d_in[2];
  const float* bc    = (const float*)d_in[3];
  const float* gamma = (const float*)d_in[4];
  const float* beta  = (const float*)d_in[5];
  const float* Wpool = (const float*)d_in[6];
  const float* bpool = (const float*)d_in[7];
  const float* W1    = (const float*)d_in[8];
  const float* b1    = (const float*)d_in[9];
  const float* W2    = (const float*)d_in[10];
  const float* b2    = (const float*)d_in[11];
  float* dout = (float*)d_out;

  char* base = (char*)d_ws; size_t o_ = 0;
  auto alloc = [&](size_t bytes)->void*{
    void* p = base + o_; o_ = (o_ + bytes + 255) & ~(size_t)255; return p;
  };
  float* B0   = (float*)alloc((size_t)NMAX*FD*4);
  float* B1   = (float*)alloc((size_t)NMAX*FD*4);
  int* eSrc   = (int*)alloc((size_t)EDG*4);
  int* eDst   = (int*)alloc((size_t)EDG*4);
  int* offv   = (int*)alloc((size_t)(NMAX+1)*4);
  int* cur    = (int*)alloc((size_t)NMAX*4);
  int* csr    = (int*)alloc((size_t)EDG*4);
  float* pbuf = (float*)alloc((size_t)NMAX*4);
  float* sbuf = (float*)alloc((size_t)NMAX*4);
  int* sel    = (int*)alloc((size_t)25000*4);
  int* rank   = (int*)alloc((size_t)(NMAX+1)*4);
  float* stats= (float*)alloc(256*4);
  unsigned* cmax = (unsigned*)alloc(384*4);
  unsigned* state= (unsigned*)alloc(64);
  unsigned* hist = (unsigned*)alloc(2*65536*4);   // hi + lo 16-bit histograms

  const int ns[3]  = {50000, 25000, 12500};
  const int bnIdx[9] = {0,1,2,3,4,5,6,6,8};   // replicate the source bug (6,6,8)
  const int EB = (EDG + 255)/256;

  const int* cs = ei;
  const int* cd = ei + EDG;

  for (int s = 0; s < 3; s++){
    int n = ns[s];
    float* X = (s == 1) ? B1 : B0;
    float* A = (s == 1) ? B0 : B1;

    hipMemsetAsync(offv, 0, (size_t)(n+1)*4, stream);
    if (s == 0){
      k_count<<<dim3(EB), dim3(256), 0, stream>>>(cs, cd, offv, EDG);
    } else {
      k_remap_count<<<dim3(EB), dim3(256), 0, stream>>>(cs, cd, eSrc, eDst, rank, n, offv, EDG);
      cs = eSrc; cd = eDst;
    }
    k_scan<<<1, 1024, 0, stream>>>(offv, cur, n);
    k_fill<<<dim3(EB), dim3(256), 0, stream>>>(cs, cd, cur, csr, EDG);

    for (int i = 0; i < 3; i++){
      int li = s*3 + i;
      const float* xr = (s == 0 && i == 0) ? x_in : (const float*)X;
      unsigned* cm = (i == 2) ? (cmax + s*FD) : (unsigned*)nullptr;
      bool pool = (i == 2) && (s < 2);
      k_agg<<<dim3((n+3)/4), dim3(256), 0, stream>>>(xr, offv, csr, A, n, stats, cm);
      k_gemm<<<dim3((n+FD-1)/FD), dim3(256), 0, stream>>>(A, Wc + (size_t)li*FD*FD, bc + li*FD, X, stats, n);
      k_bn<<<dim3((n+15)/16), dim3(256), 0, stream>>>(X, stats, gamma + bnIdx[li]*FD, beta + bnIdx[li]*FD,
                                                      n, 1.f/(float)n, cm,
                                                      pool ? (Wpool + s*FD) : (const float*)nullptr,
                                                      pool ? pbuf : (float*)nullptr);
    }

    if (s < 2){
      int k = (s == 0) ? 25000 : 12500;
      k_score<<<dim3((n+255)/256), dim3(256), 0, stream>>>(pbuf, offv, csr, bpool, s, sbuf, n);
      hipMemsetAsync(hist, 0, 2*65536*4, stream);
      k_hist_hi<<<dim3((n+255)/256), dim3(256), 0, stream>>>(sbuf, n, hist);
      k_pick<<<1, 1024, 0, stream>>>(hist, state, k, 0);
      k_hist_lo<<<dim3((n+255)/256), dim3(256), 0, stream>>>(sbuf, n, state, hist + 65536);
      k_pick<<<1, 1024, 0, stream>>>(hist + 65536, state, k, 1);
      k_compact<<<dim3((n+256)/256), dim3(256), 0, stream>>>(sbuf, state, rank, sel, n, k);
      k_gather<<<dim3((k+3)/4), dim3(256), 0, stream>>>(X, sel, sbuf, A, k);
    }
  }
  k_final<<<1, 384, 0, stream>>>(cmax, W1, b1, W2, b2, dout);
}

// Round 6
// 1042.590 us; speedup vs baseline: 1.2800x; 1.1171x over previous
//
#include <hip/hip_runtime.h>

constexpr int FD   = 128;
constexpr int NMAX = 50000;
constexpr int EDG  = 800000;

static __device__ __forceinline__ unsigned enc(float f){
  unsigned u = __float_as_uint(f);
  return (u & 0x80000000u) ? ~u : (u | 0x80000000u);
}
static __device__ __forceinline__ float dec(unsigned e){
  unsigned u = (e & 0x80000000u) ? (e ^ 0x80000000u) : ~e;
  return __uint_as_float(u);
}

// ---------------- CSR build ----------------
__global__ void k_count(const int* __restrict__ src, const int* __restrict__ dst,
                        int* __restrict__ deg, int E){
  int e = blockIdx.x*256 + threadIdx.x;
  if (e >= E) return;
  int s = src[e], d = dst[e];
  if (s != d) atomicAdd(&deg[d], 1);
}

__global__ void k_remap_count(const int* __restrict__ sIn, const int* __restrict__ dIn,
                              int* __restrict__ sOut, int* __restrict__ dOut,
                              const int* __restrict__ rank, int kNew,
                              int* __restrict__ deg, int E){
  int e = blockIdx.x*256 + threadIdx.x;
  if (e >= E) return;
  int s = sIn[e], d = dIn[e];
  int rs = rank[s], rd = rank[d];
  bool ok = (rs >= 0) && (rd >= 0);
  int os = ok ? rs : kNew, od = ok ? rd : kNew;
  sOut[e] = os; dOut[e] = od;
  if (os != od) atomicAdd(&deg[od], 1);
}

__global__ void k_scan(int* __restrict__ off, int* __restrict__ cur, int n){
  __shared__ int wsum[16];
  __shared__ int carry;
  int tid = threadIdx.x, lane = tid & 63, wid = tid >> 6;
  if (tid == 0) carry = 0;
  __syncthreads();
  for (int base = 0; base < n; base += 1024){
    int v = base + tid;
    int x = (v < n) ? off[v] : 0;
    int val = x;
    #pragma unroll
    for (int o = 1; o < 64; o <<= 1){ int t = __shfl_up(val, o); if (lane >= o) val += t; }
    if (lane == 63) wsum[wid] = val;
    __syncthreads();
    if (tid < 16){
      int v2 = wsum[tid];
      #pragma unroll
      for (int o = 1; o < 16; o <<= 1){ int t = __shfl_up(v2, o); if (tid >= o) v2 += t; }
      wsum[tid] = v2;
    }
    __syncthreads();
    int add = (wid > 0) ? wsum[wid-1] : 0;
    int incl = val + add;
    int c0 = carry;
    if (v < n){ int e0 = c0 + incl - x; off[v] = e0; cur[v] = e0; }
    __syncthreads();
    if (tid == 0) carry = c0 + wsum[15];
    __syncthreads();
  }
  if (tid == 0) off[n] = carry;
}

__global__ void k_fill(const int* __restrict__ src, const int* __restrict__ dst,
                       int* __restrict__ cur, int* __restrict__ csr, int E){
  int e = blockIdx.x*256 + threadIdx.x;
  if (e >= E) return;
  int s = src[e], d = dst[e];
  if (s != d){ int pos = atomicAdd(&cur[d], 1); csr[pos] = s; }
}

// -------- aggregation with fused BN-affine of the PREVIOUS layer --------
// out = a ∘ [(sum_nb x + x)/(deg+1)] + b   (a=1,b=0 when st==null)
__global__ __launch_bounds__(256) void k_agg(const float* __restrict__ X,
    const int* __restrict__ off, const int* __restrict__ csr,
    float* __restrict__ AGG, int n,
    const float* __restrict__ st, const float* __restrict__ g,
    const float* __restrict__ bt, float invn){
  int tid = threadIdx.x;
  int v = blockIdx.x*4 + (tid >> 6);
  if (v >= n) return;
  int lane = tid & 63;
  int c = lane * 2;
  float ax = 1.f, ay = 1.f, bx = 0.f, by = 0.f;
  if (st){
    float ma = st[c]*invn, mb = st[c+1]*invn;
    float va = st[FD+c]*invn - ma*ma, vb = st[FD+c+1]*invn - mb*mb;
    ax = g[c]*rsqrtf(va + 1e-5f);  ay = g[c+1]*rsqrtf(vb + 1e-5f);
    bx = bt[c] - ma*ax;            by = bt[c+1] - mb*ay;
  }
  int b = off[v], e = off[v+1];
  int deg = e - b;
  float2 s = *(const float2*)(X + (size_t)v*FD + c);
  int j = 0;
  while (j < deg){
    int cnt = deg - j; if (cnt > 64) cnt = 64;
    int myu = (j + lane < deg) ? csr[b + j + lane] : 0;
    int t = 0;
    for (; t + 4 <= cnt; t += 4){
      int u0 = __shfl(myu, t);
      int u1 = __shfl(myu, t+1);
      int u2 = __shfl(myu, t+2);
      int u3 = __shfl(myu, t+3);
      float2 t0 = *(const float2*)(X + (size_t)u0*FD + c);
      float2 t1 = *(const float2*)(X + (size_t)u1*FD + c);
      float2 t2 = *(const float2*)(X + (size_t)u2*FD + c);
      float2 t3 = *(const float2*)(X + (size_t)u3*FD + c);
      s.x += t0.x + t1.x + t2.x + t3.x;
      s.y += t0.y + t1.y + t2.y + t3.y;
    }
    for (; t < cnt; t++){
      int u = __shfl(myu, t);
      float2 tt = *(const float2*)(X + (size_t)u*FD + c);
      s.x += tt.x; s.y += tt.y;
    }
    j += cnt;
  }
  float inv = 1.f / (float)(deg + 1);
  float2 o;
  o.x = s.x*inv*ax + bx;
  o.y = s.y*inv*ay + by;
  *(float2*)(AGG + (size_t)v*FD + c) = o;
}

// ---- GEMM + bias + L2norm + ReLU + BN-stats (+ col max/min for readout layers) ----
__global__ __launch_bounds__(256,2) void k_gemm(const float* __restrict__ A,
    const float* __restrict__ W, const float* __restrict__ bias,
    float* __restrict__ Y, float* __restrict__ stats, int n,
    unsigned* __restrict__ cmx, unsigned* __restrict__ cmn){
  __shared__ float sW[FD*FD];
  __shared__ float ss[4][FD];
  __shared__ float sq_[4][FD];
  __shared__ float smx[4][FD];
  __shared__ float smn[4][FD];
  int tid = threadIdx.x;
  {
    const float4* Wg = (const float4*)W; float4* Ws = (float4*)sW;
    for (int i = tid; i < FD*FD/4; i += 256) Ws[i] = Wg[i];
  }
  __syncthreads();
  int tc = tid & 15;
  int tr = tid >> 4;
  int rbase = blockIdx.x*FD + tr*8;
  float acc[8][8];
  #pragma unroll
  for (int i = 0; i < 8; i++)
    #pragma unroll
    for (int j = 0; j < 8; j++) acc[i][j] = 0.f;

  for (int k4 = 0; k4 < FD; k4 += 4){
    float4 a[8];
    #pragma unroll
    for (int i = 0; i < 8; i++){
      int r = rbase + i; if (r >= n) r = n - 1;
      a[i] = *(const float4*)(A + (size_t)r*FD + k4);
    }
    #pragma unroll
    for (int kk = 0; kk < 4; kk++){
      const float* wr = &sW[(k4+kk)*FD + tc*8];
      float4 w0 = *(const float4*)wr, w1 = *(const float4*)(wr+4);
      #pragma unroll
      for (int i = 0; i < 8; i++){
        float av = (kk==0) ? a[i].x : (kk==1) ? a[i].y : (kk==2) ? a[i].z : a[i].w;
        acc[i][0] += av*w0.x; acc[i][1] += av*w0.y; acc[i][2] += av*w0.z; acc[i][3] += av*w0.w;
        acc[i][4] += av*w1.x; acc[i][5] += av*w1.y; acc[i][6] += av*w1.z; acc[i][7] += av*w1.w;
      }
    }
  }
  float bx[8];
  {
    const float* bp = bias + tc*8;
    #pragma unroll
    for (int j = 0; j < 8; j++) bx[j] = bp[j];
  }
  float cs[8], cq[8], mxv[8], mnv[8];
  #pragma unroll
  for (int j = 0; j < 8; j++){ cs[j]=0.f; cq[j]=0.f; mxv[j]=-3.4e38f; mnv[j]=3.4e38f; }
  #pragma unroll
  for (int i = 0; i < 8; i++){
    int r = rbase + i;
    bool valid = (r < n);
    float y[8]; float sq = 0.f;
    #pragma unroll
    for (int j = 0; j < 8; j++){ y[j] = acc[i][j] + bx[j]; sq += y[j]*y[j]; }
    sq += __shfl_xor(sq,1); sq += __shfl_xor(sq,2); sq += __shfl_xor(sq,4); sq += __shfl_xor(sq,8);
    float nrm = sqrtf(sq);
    float sc = 1.f / fmaxf(nrm, 1e-12f);
    #pragma unroll
    for (int j = 0; j < 8; j++){ y[j] *= sc; y[j] = fmaxf(y[j], 0.f); }
    if (valid){
      float* yo = Y + (size_t)r*FD + tc*8;
      *(float4*)yo     = make_float4(y[0],y[1],y[2],y[3]);
      *(float4*)(yo+4) = make_float4(y[4],y[5],y[6],y[7]);
      #pragma unroll
      for (int j = 0; j < 8; j++){
        cs[j] += y[j]; cq[j] += y[j]*y[j];
        mxv[j] = fmaxf(mxv[j], y[j]); mnv[j] = fminf(mnv[j], y[j]);
      }
    }
  }
  #pragma unroll
  for (int j = 0; j < 8; j++){
    cs[j] += __shfl_xor(cs[j],16); cs[j] += __shfl_xor(cs[j],32);
    cq[j] += __shfl_xor(cq[j],16); cq[j] += __shfl_xor(cq[j],32);
    mxv[j] = fmaxf(mxv[j], __shfl_xor(mxv[j],16)); mxv[j] = fmaxf(mxv[j], __shfl_xor(mxv[j],32));
    mnv[j] = fminf(mnv[j], __shfl_xor(mnv[j],16)); mnv[j] = fminf(mnv[j], __shfl_xor(mnv[j],32));
  }
  int wv = tid >> 6, lane = tid & 63;
  if (lane < 16){
    #pragma unroll
    for (int j = 0; j < 8; j++){
      ss[wv][tc*8+j] = cs[j]; sq_[wv][tc*8+j] = cq[j];
      smx[wv][tc*8+j] = mxv[j]; smn[wv][tc*8+j] = mnv[j];
    }
  }
  __syncthreads();
  if (tid < FD){
    float s_ = ss[0][tid]+ss[1][tid]+ss[2][tid]+ss[3][tid];
    float q_ = sq_[0][tid]+sq_[1][tid]+sq_[2][tid]+sq_[3][tid];
    atomicAdd(&stats[tid], s_);
    atomicAdd(&stats[FD+tid], q_);
    if (cmx){
      float mx = fmaxf(fmaxf(smx[0][tid],smx[1][tid]), fmaxf(smx[2][tid],smx[3][tid]));
      float mn = fminf(fminf(smn[0][tid],smn[1][tid]), fminf(smn[2][tid],smn[3][tid]));
      atomicMax(&cmx[tid], enc(mx));
      atomicMin(&cmn[tid], enc(mn));
    }
  }
}

// -------- pool dot with fused BN-affine: p[v] = (a∘x + b) · wp --------
__global__ __launch_bounds__(256) void k_dotp(const float* __restrict__ X,
    const float* __restrict__ wp,
    const float* __restrict__ st, const float* __restrict__ g,
    const float* __restrict__ bt, float invn,
    float* __restrict__ p, int n){
  int tid = threadIdx.x;
  int v = blockIdx.x*4 + (tid >> 6), lane = tid & 63;
  if (v >= n) return;
  int c = lane * 2;
  float ma = st[c]*invn, mb = st[c+1]*invn;
  float va = st[FD+c]*invn - ma*ma, vb = st[FD+c+1]*invn - mb*mb;
  float ax = g[c]*rsqrtf(va + 1e-5f), ay = g[c+1]*rsqrtf(vb + 1e-5f);
  float bx = bt[c] - ma*ax,           by = bt[c+1] - mb*ay;
  float2 x = *(const float2*)(X + (size_t)v*FD + c);
  float2 w = *(const float2*)(wp + c);
  float s = (ax*x.x + bx)*w.x + (ay*x.y + by)*w.y;
  s += __shfl_xor(s,1); s += __shfl_xor(s,2); s += __shfl_xor(s,4);
  s += __shfl_xor(s,8); s += __shfl_xor(s,16); s += __shfl_xor(s,32);
  if (lane == 0) p[v] = s;
}

__global__ void k_score(const float* __restrict__ p, const int* __restrict__ off,
    const int* __restrict__ csr, const float* __restrict__ bpool, int pi,
    float* __restrict__ score, int n){
  int v = blockIdx.x*256 + threadIdx.x;
  if (v >= n) return;
  int b = off[v], e = off[v+1];
  float s = p[v];
  for (int j = b; j < e; j++) s += p[csr[j]];
  score[v] = tanhf(s / (float)(e - b + 1) + bpool[pi]);
}

// -------- multi-block radix select (two 16-bit digits) --------
__global__ void k_hist_hi(const float* __restrict__ score, int n, unsigned* __restrict__ hist){
  int v = blockIdx.x*256 + threadIdx.x;
  if (v >= n) return;
  unsigned key = enc(score[v]);
  atomicAdd(&hist[key >> 16], 1u);
}

__global__ void k_hist_lo(const float* __restrict__ score, int n,
                          const unsigned* __restrict__ state, unsigned* __restrict__ hist){
  int v = blockIdx.x*256 + threadIdx.x;
  if (v >= n) return;
  unsigned key = enc(score[v]);
  if ((key >> 16) == state[5]) atomicAdd(&hist[key & 0xFFFFu], 1u);
}

__global__ __launch_bounds__(1024) void k_pick(const unsigned* __restrict__ hist,
                                               unsigned* __restrict__ state, int k, int pass){
  __shared__ unsigned wsum[16];
  int tid = threadIdx.x;
  unsigned want = (pass == 0) ? (unsigned)k : state[4];
  unsigned prevAbove = (pass == 0) ? 0u : state[1];
  int chunk = 1023 - tid;
  const unsigned* hbase = hist + chunk*64;
  unsigned csum = 0;
  #pragma unroll
  for (int j = 0; j < 64; j++) csum += hbase[j];
  unsigned val = csum;
  int lane = tid & 63, wid = tid >> 6;
  #pragma unroll
  for (int o = 1; o < 64; o <<= 1){ unsigned t = __shfl_up(val, o); if (lane >= o) val += t; }
  if (lane == 63) wsum[wid] = val;
  __syncthreads();
  if (tid < 16){
    unsigned v2 = wsum[tid];
    #pragma unroll
    for (int o = 1; o < 16; o <<= 1){ unsigned t = __shfl_up(v2, o); if (tid >= o) v2 += t; }
    wsum[tid] = v2;
  }
  __syncthreads();
  unsigned incl = val + ((wid > 0) ? wsum[wid-1] : 0u);
  unsigned excl = incl - csum;
  if (excl < want && incl >= want){
    unsigned cum = excl, above = 0; int bsel = 0;
    for (int j = 63; j >= 0; j--){
      unsigned cc = hbase[j];
      if (cum + cc >= want){ bsel = j; above = cum; break; }
      cum += cc;
    }
    unsigned bucket = (unsigned)(chunk*64 + bsel);
    if (pass == 0){
      state[5] = bucket;
      state[1] = prevAbove + above;
      state[4] = want - above;
    } else {
      unsigned T = (state[5] << 16) | bucket;
      unsigned totAbove = prevAbove + above;
      state[0] = T; state[1] = totAbove; state[2] = 0u; state[3] = totAbove;
    }
  }
}

__global__ void k_compact(const float* __restrict__ score, unsigned* __restrict__ state,
    int* __restrict__ rank, int* __restrict__ sel, int n, int k){
  int v = blockIdx.x*256 + threadIdx.x;
  if (v > n) return;
  if (v == n){ rank[n] = -1; return; }
  unsigned T = state[0];
  unsigned key = enc(score[v]);
  int slot = -1;
  if (key > T) slot = (int)atomicAdd(&state[2], 1u);
  else if (key == T){ unsigned t = atomicAdd(&state[3], 1u); if (t < (unsigned)k) slot = (int)t; }
  rank[v] = slot;
  if (slot >= 0) sel[slot] = v;
}

// -------- gather with fused BN-affine: out = (a∘x + b) * score --------
__global__ __launch_bounds__(256) void k_gather(const float* __restrict__ X,
    const int* __restrict__ sel, const float* __restrict__ score,
    const float* __restrict__ st, const float* __restrict__ g,
    const float* __restrict__ bt, float invn,
    float* __restrict__ XO, int k){
  int j = blockIdx.x*4 + (threadIdx.x >> 6), lane = threadIdx.x & 63;
  if (j >= k) return;
  int c = lane * 2;
  float ma = st[c]*invn, mb = st[c+1]*invn;
  float va = st[FD+c]*invn - ma*ma, vb = st[FD+c+1]*invn - mb*mb;
  float ax = g[c]*rsqrtf(va + 1e-5f), ay = g[c+1]*rsqrtf(vb + 1e-5f);
  float bx = bt[c] - ma*ax,           by = bt[c+1] - mb*ay;
  int u = sel[j];
  float sc = score[u];
  float2 t = *(const float2*)(X + (size_t)u*FD + c);
  t.x = (ax*t.x + bx)*sc; t.y = (ay*t.y + by)*sc;
  *(float2*)(XO + (size_t)j*FD + c) = t;
}

// -------- final: BN'd col-max readout (sign-aware from pre-BN max/min) + MLP --------
__global__ void k_final(const unsigned* __restrict__ cmx, const unsigned* __restrict__ cmn,
    const float* __restrict__ stats, const float* __restrict__ gamma,
    const float* __restrict__ beta,
    const float* __restrict__ W1, const float* __restrict__ b1,
    const float* __restrict__ W2, const float* __restrict__ b2,
    float* __restrict__ out){
  __shared__ float h[384];
  __shared__ float h1[50];
  int tid = threadIdx.x;
  if (tid < 384){
    int s = tid >> 7, c = tid & 127;
    const int liR[3] = {2,5,8};
    const float nsf[3] = {50000.f, 25000.f, 12500.f};
    int li = liR[s];
    const float* st = stats + (size_t)li*256;
    float invn = 1.f / nsf[s];
    float m = st[c]*invn, vv = st[FD+c]*invn - m*m;
    float a = gamma[(size_t)li*FD+c]*rsqrtf(vv + 1e-5f);
    float bb = beta[(size_t)li*FD+c] - m*a;
    float mx = dec(cmx[tid]), mn = dec(cmn[tid]);
    h[tid] = (a >= 0.f) ? (a*mx + bb) : (a*mn + bb);
  }
  __syncthreads();
  if (tid < 50){
    float acc = b1[tid];
    for (int i = 0; i < 384; i++) acc += h[i]*W1[i*50 + tid];
    h1[tid] = fmaxf(acc, 0.f);
  }
  __syncthreads();
  if (tid < 5){
    float acc = b2[tid];
    for (int i = 0; i < 50; i++) acc += h1[i]*W2[i*5 + tid];
    out[tid] = acc;
  }
}

extern "C" void kernel_launch(void* const* d_in, const int* in_sizes, int n_in,
                              void* d_out, int out_size, void* d_ws, size_t ws_size,
                              hipStream_t stream){
  (void)in_sizes; (void)n_in; (void)out_size; (void)ws_size;
  const float* x_in  = (const float*)d_in[0];
  const int*   ei    = (const int*)d_in[1];
  const float* Wc    = (const float*)d_in[2];
  const float* bc    = (const float*)d_in[3];
  const float* gamma = (const float*)d_in[4];
  const float* beta  = (const float*)d_in[5];
  const float* Wpool = (const float*)d_in[6];
  const float* bpool = (const float*)d_in[7];
  const float* W1    = (const float*)d_in[8];
  const float* b1    = (const float*)d_in[9];
  const float* W2    = (const float*)d_in[10];
  const float* b2    = (const float*)d_in[11];
  float* dout = (float*)d_out;

  char* base = (char*)d_ws; size_t o_ = 0;
  auto alloc = [&](size_t bytes)->void*{
    void* p = base + o_; o_ = (o_ + bytes + 255) & ~(size_t)255; return p;
  };
  float* B0   = (float*)alloc((size_t)NMAX*FD*4);
  float* B1   = (float*)alloc((size_t)NMAX*FD*4);
  int* eSrc   = (int*)alloc((size_t)EDG*4);
  int* eDst   = (int*)alloc((size_t)EDG*4);
  int* offv   = (int*)alloc((size_t)(NMAX+1)*4);
  int* cur    = (int*)alloc((size_t)NMAX*4);
  int* csr    = (int*)alloc((size_t)EDG*4);
  float* pbuf = (float*)alloc((size_t)NMAX*4);
  float* sbuf = (float*)alloc((size_t)NMAX*4);
  int* sel    = (int*)alloc((size_t)25000*4);
  int* rank   = (int*)alloc((size_t)(NMAX+1)*4);
  float* stats= (float*)alloc(9*256*4);          // per-layer BN sums/sumsq
  unsigned* cmx = (unsigned*)alloc(384*4);       // pre-BN col max, 3 readout layers
  unsigned* cmn = (unsigned*)alloc(384*4);       // pre-BN col min
  unsigned* state= (unsigned*)alloc(64);
  unsigned* hist = (unsigned*)alloc(2*65536*4);

  const int ns[3]  = {50000, 25000, 12500};
  const int bnIdx[9] = {0,1,2,3,4,5,6,6,8};   // replicate the source bug (6,6,8)
  const int EB = (EDG + 255)/256;

  hipMemsetAsync(stats, 0, 9*256*4, stream);
  hipMemsetAsync(cmx, 0x00, 384*4, stream);    // enc-smallest
  hipMemsetAsync(cmn, 0xFF, 384*4, stream);    // enc-largest

  const int* cs = ei;
  const int* cd = ei + EDG;

  for (int s = 0; s < 3; s++){
    int n = ns[s];
    float fin = 1.f/(float)n;
    float* X = (s == 1) ? B1 : B0;
    float* A = (s == 1) ? B0 : B1;

    hipMemsetAsync(offv, 0, (size_t)(n+1)*4, stream);
    if (s == 0){
      k_count<<<dim3(EB), dim3(256), 0, stream>>>(cs, cd, offv, EDG);
    } else {
      k_remap_count<<<dim3(EB), dim3(256), 0, stream>>>(cs, cd, eSrc, eDst, rank, n, offv, EDG);
      cs = eSrc; cd = eDst;
    }
    k_scan<<<1, 1024, 0, stream>>>(offv, cur, n);
    k_fill<<<dim3(EB), dim3(256), 0, stream>>>(cs, cd, cur, csr, EDG);

    for (int i = 0; i < 3; i++){
      int li = s*3 + i;
      const float* xr = (s == 0 && i == 0) ? x_in : (const float*)X;
      // BN-affine of the layer whose output we aggregate (identity at stage entry).
      const float* stPrev = (i == 0) ? (const float*)nullptr : stats + (size_t)(li-1)*256;
      int gb = (i == 0) ? 0 : bnIdx[li-1];
      bool rd = (i == 2);
      k_agg<<<dim3((n+3)/4), dim3(256), 0, stream>>>(xr, offv, csr, A, n,
                                                     stPrev, gamma + (size_t)gb*FD, beta + (size_t)gb*FD, fin);
      k_gemm<<<dim3((n+FD-1)/FD), dim3(256), 0, stream>>>(A, Wc + (size_t)li*FD*FD, bc + li*FD, X,
                                                          stats + (size_t)li*256, n,
                                                          rd ? (cmx + s*FD) : (unsigned*)nullptr,
                                                          rd ? (cmn + s*FD) : (unsigned*)nullptr);
    }

    if (s < 2){
      int k = (s == 0) ? 25000 : 12500;
      int li2 = s*3 + 2;
      const float* st2 = stats + (size_t)li2*256;
      const float* g2 = gamma + (size_t)bnIdx[li2]*FD;
      const float* bt2 = beta + (size_t)bnIdx[li2]*FD;
      k_dotp<<<dim3((n+3)/4), dim3(256), 0, stream>>>(X, Wpool + s*FD, st2, g2, bt2, fin, pbuf, n);
      k_score<<<dim3((n+255)/256), dim3(256), 0, stream>>>(pbuf, offv, csr, bpool, s, sbuf, n);
      hipMemsetAsync(hist, 0, 2*65536*4, stream);
      k_hist_hi<<<dim3((n+255)/256), dim3(256), 0, stream>>>(sbuf, n, hist);
      k_pick<<<1, 1024, 0, stream>>>(hist, state, k, 0);
      k_hist_lo<<<dim3((n+255)/256), dim3(256), 0, stream>>>(sbuf, n, state, hist + 65536);
      k_pick<<<1, 1024, 0, stream>>>(hist + 65536, state, k, 1);
      k_compact<<<dim3((n+256)/256), dim3(256), 0, stream>>>(sbuf, state, rank, sel, n, k);
      k_gather<<<dim3((k+3)/4), dim3(256), 0, stream>>>(X, sel, sbuf, st2, g2, bt2, fin, A, k);
    }
  }
  k_final<<<1, 384, 0, stream>>>(cmx, cmn, stats, gamma, beta, W1, b1, W2, b2, dout);
}

// Round 7
// 962.345 us; speedup vs baseline: 1.3867x; 1.0834x over previous
//
#include <hip/hip_runtime.h>

constexpr int FD   = 128;
constexpr int NMAX = 50000;
constexpr int EDG  = 800000;

static __device__ __forceinline__ unsigned enc(float f){
  unsigned u = __float_as_uint(f);
  return (u & 0x80000000u) ? ~u : (u | 0x80000000u);
}
static __device__ __forceinline__ float dec(unsigned e){
  unsigned u = (e & 0x80000000u) ? (e ^ 0x80000000u) : ~e;
  return __uint_as_float(u);
}

// ---------------- CSR build ----------------
__global__ void k_count(const int* __restrict__ src, const int* __restrict__ dst,
                        int* __restrict__ deg, int E){
  int e = blockIdx.x*256 + threadIdx.x;
  if (e >= E) return;
  int s = src[e], d = dst[e];
  if (s != d) atomicAdd(&deg[d], 1);
}

__global__ void k_remap_count(const int* __restrict__ sIn, const int* __restrict__ dIn,
                              int* __restrict__ sOut, int* __restrict__ dOut,
                              const int* __restrict__ rank, int kNew,
                              int* __restrict__ deg, int E){
  int e = blockIdx.x*256 + threadIdx.x;
  if (e >= E) return;
  int s = sIn[e], d = dIn[e];
  int rs = rank[s], rd = rank[d];
  bool ok = (rs >= 0) && (rd >= 0);
  int os = ok ? rs : kNew, od = ok ? rd : kNew;
  sOut[e] = os; dOut[e] = od;
  if (os != od) atomicAdd(&deg[od], 1);
}

// ---- parallel offset allocation: per-block scan + one atomic block base ----
// (CSR slot order across blocks is arbitrary — semantically irrelevant)
__global__ __launch_bounds__(256) void k_offsets(const int* __restrict__ deg,
    int* __restrict__ start, int* __restrict__ cur, int* __restrict__ total, int n){
  __shared__ int wsum[4];
  __shared__ int sbase;
  int tid = threadIdx.x, lane = tid & 63, wid = tid >> 6;
  int v = blockIdx.x*256 + tid;
  int x = (v < n) ? deg[v] : 0;
  int val = x;
  #pragma unroll
  for (int o = 1; o < 64; o <<= 1){ int t = __shfl_up(val, o); if (lane >= o) val += t; }
  if (lane == 63) wsum[wid] = val;
  __syncthreads();
  if (tid == 0){
    int t0 = wsum[0], t1 = wsum[1], t2 = wsum[2], t3 = wsum[3];
    sbase = atomicAdd(total, t0+t1+t2+t3);
    wsum[0] = 0; wsum[1] = t0; wsum[2] = t0+t1; wsum[3] = t0+t1+t2;
  }
  __syncthreads();
  int excl = (val - x) + wsum[wid] + sbase;
  if (v < n){ start[v] = excl; cur[v] = excl; }
}

__global__ void k_fill(const int* __restrict__ src, const int* __restrict__ dst,
                       int* __restrict__ cur, int* __restrict__ csr, int E){
  int e = blockIdx.x*256 + threadIdx.x;
  if (e >= E) return;
  int s = src[e], d = dst[e];
  if (s != d){ int pos = atomicAdd(&cur[d], 1); csr[pos] = s; }
}

// -------- aggregation with fused BN-affine of the PREVIOUS layer, 8-way ILP --------
__global__ __launch_bounds__(256) void k_agg(const float* __restrict__ X,
    const int* __restrict__ start, const int* __restrict__ degb,
    const int* __restrict__ csr,
    float* __restrict__ AGG, int n,
    const float* __restrict__ st, const float* __restrict__ g,
    const float* __restrict__ bt, float invn){
  int tid = threadIdx.x;
  int v = blockIdx.x*4 + (tid >> 6);
  if (v >= n) return;
  int lane = tid & 63;
  int c = lane * 2;
  float ax = 1.f, ay = 1.f, bx = 0.f, by = 0.f;
  if (st){
    float ma = st[c]*invn, mb = st[c+1]*invn;
    float va = st[FD+c]*invn - ma*ma, vb = st[FD+c+1]*invn - mb*mb;
    ax = g[c]*rsqrtf(va + 1e-5f);  ay = g[c+1]*rsqrtf(vb + 1e-5f);
    bx = bt[c] - ma*ax;            by = bt[c+1] - mb*ay;
  }
  int b = start[v];
  int deg = degb[v];
  float2 s = *(const float2*)(X + (size_t)v*FD + c);
  int j = 0;
  while (j < deg){
    int cnt = deg - j; if (cnt > 64) cnt = 64;
    int myu = (j + lane < deg) ? csr[b + j + lane] : 0;
    int t = 0;
    for (; t + 8 <= cnt; t += 8){
      int u0 = __shfl(myu, t),   u1 = __shfl(myu, t+1);
      int u2 = __shfl(myu, t+2), u3 = __shfl(myu, t+3);
      int u4 = __shfl(myu, t+4), u5 = __shfl(myu, t+5);
      int u6 = __shfl(myu, t+6), u7 = __shfl(myu, t+7);
      float2 t0 = *(const float2*)(X + (size_t)u0*FD + c);
      float2 t1 = *(const float2*)(X + (size_t)u1*FD + c);
      float2 t2 = *(const float2*)(X + (size_t)u2*FD + c);
      float2 t3 = *(const float2*)(X + (size_t)u3*FD + c);
      float2 t4 = *(const float2*)(X + (size_t)u4*FD + c);
      float2 t5 = *(const float2*)(X + (size_t)u5*FD + c);
      float2 t6 = *(const float2*)(X + (size_t)u6*FD + c);
      float2 t7 = *(const float2*)(X + (size_t)u7*FD + c);
      s.x += ((t0.x + t1.x) + (t2.x + t3.x)) + ((t4.x + t5.x) + (t6.x + t7.x));
      s.y += ((t0.y + t1.y) + (t2.y + t3.y)) + ((t4.y + t5.y) + (t6.y + t7.y));
    }
    for (; t + 4 <= cnt; t += 4){
      int u0 = __shfl(myu, t),   u1 = __shfl(myu, t+1);
      int u2 = __shfl(myu, t+2), u3 = __shfl(myu, t+3);
      float2 t0 = *(const float2*)(X + (size_t)u0*FD + c);
      float2 t1 = *(const float2*)(X + (size_t)u1*FD + c);
      float2 t2 = *(const float2*)(X + (size_t)u2*FD + c);
      float2 t3 = *(const float2*)(X + (size_t)u3*FD + c);
      s.x += (t0.x + t1.x) + (t2.x + t3.x);
      s.y += (t0.y + t1.y) + (t2.y + t3.y);
    }
    for (; t < cnt; t++){
      int u = __shfl(myu, t);
      float2 tt = *(const float2*)(X + (size_t)u*FD + c);
      s.x += tt.x; s.y += tt.y;
    }
    j += cnt;
  }
  float inv = 1.f / (float)(deg + 1);
  float2 o;
  o.x = s.x*inv*ax + bx;
  o.y = s.y*inv*ay + by;
  *(float2*)(AGG + (size_t)v*FD + c) = o;
}

// ---- GEMM + bias + L2norm + ReLU + BN-stats (+ col max/min for readout layers) ----
__global__ __launch_bounds__(256,2) void k_gemm(const float* __restrict__ A,
    const float* __restrict__ W, const float* __restrict__ bias,
    float* __restrict__ Y, float* __restrict__ stats, int n,
    unsigned* __restrict__ cmx, unsigned* __restrict__ cmn){
  __shared__ float sW[FD*FD];
  __shared__ float ss[4][FD];
  __shared__ float sq_[4][FD];
  __shared__ float smx[4][FD];
  __shared__ float smn[4][FD];
  int tid = threadIdx.x;
  {
    const float4* Wg = (const float4*)W; float4* Ws = (float4*)sW;
    for (int i = tid; i < FD*FD/4; i += 256) Ws[i] = Wg[i];
  }
  __syncthreads();
  int tc = tid & 15;
  int tr = tid >> 4;
  int rbase = blockIdx.x*FD + tr*8;
  float acc[8][8];
  #pragma unroll
  for (int i = 0; i < 8; i++)
    #pragma unroll
    for (int j = 0; j < 8; j++) acc[i][j] = 0.f;

  for (int k4 = 0; k4 < FD; k4 += 4){
    float4 a[8];
    #pragma unroll
    for (int i = 0; i < 8; i++){
      int r = rbase + i; if (r >= n) r = n - 1;
      a[i] = *(const float4*)(A + (size_t)r*FD + k4);
    }
    #pragma unroll
    for (int kk = 0; kk < 4; kk++){
      const float* wr = &sW[(k4+kk)*FD + tc*8];
      float4 w0 = *(const float4*)wr, w1 = *(const float4*)(wr+4);
      #pragma unroll
      for (int i = 0; i < 8; i++){
        float av = (kk==0) ? a[i].x : (kk==1) ? a[i].y : (kk==2) ? a[i].z : a[i].w;
        acc[i][0] += av*w0.x; acc[i][1] += av*w0.y; acc[i][2] += av*w0.z; acc[i][3] += av*w0.w;
        acc[i][4] += av*w1.x; acc[i][5] += av*w1.y; acc[i][6] += av*w1.z; acc[i][7] += av*w1.w;
      }
    }
  }
  float bx[8];
  {
    const float* bp = bias + tc*8;
    #pragma unroll
    for (int j = 0; j < 8; j++) bx[j] = bp[j];
  }
  float cs[8], cq[8], mxv[8], mnv[8];
  #pragma unroll
  for (int j = 0; j < 8; j++){ cs[j]=0.f; cq[j]=0.f; mxv[j]=-3.4e38f; mnv[j]=3.4e38f; }
  #pragma unroll
  for (int i = 0; i < 8; i++){
    int r = rbase + i;
    bool valid = (r < n);
    float y[8]; float sq = 0.f;
    #pragma unroll
    for (int j = 0; j < 8; j++){ y[j] = acc[i][j] + bx[j]; sq += y[j]*y[j]; }
    sq += __shfl_xor(sq,1); sq += __shfl_xor(sq,2); sq += __shfl_xor(sq,4); sq += __shfl_xor(sq,8);
    float nrm = sqrtf(sq);
    float sc = 1.f / fmaxf(nrm, 1e-12f);
    #pragma unroll
    for (int j = 0; j < 8; j++){ y[j] *= sc; y[j] = fmaxf(y[j], 0.f); }
    if (valid){
      float* yo = Y + (size_t)r*FD + tc*8;
      *(float4*)yo     = make_float4(y[0],y[1],y[2],y[3]);
      *(float4*)(yo+4) = make_float4(y[4],y[5],y[6],y[7]);
      #pragma unroll
      for (int j = 0; j < 8; j++){
        cs[j] += y[j]; cq[j] += y[j]*y[j];
        mxv[j] = fmaxf(mxv[j], y[j]); mnv[j] = fminf(mnv[j], y[j]);
      }
    }
  }
  #pragma unroll
  for (int j = 0; j < 8; j++){
    cs[j] += __shfl_xor(cs[j],16); cs[j] += __shfl_xor(cs[j],32);
    cq[j] += __shfl_xor(cq[j],16); cq[j] += __shfl_xor(cq[j],32);
    mxv[j] = fmaxf(mxv[j], __shfl_xor(mxv[j],16)); mxv[j] = fmaxf(mxv[j], __shfl_xor(mxv[j],32));
    mnv[j] = fminf(mnv[j], __shfl_xor(mnv[j],16)); mnv[j] = fminf(mnv[j], __shfl_xor(mnv[j],32));
  }
  int wv = tid >> 6, lane = tid & 63;
  if (lane < 16){
    #pragma unroll
    for (int j = 0; j < 8; j++){
      ss[wv][tc*8+j] = cs[j]; sq_[wv][tc*8+j] = cq[j];
      smx[wv][tc*8+j] = mxv[j]; smn[wv][tc*8+j] = mnv[j];
    }
  }
  __syncthreads();
  if (tid < FD){
    float s_ = ss[0][tid]+ss[1][tid]+ss[2][tid]+ss[3][tid];
    float q_ = sq_[0][tid]+sq_[1][tid]+sq_[2][tid]+sq_[3][tid];
    atomicAdd(&stats[tid], s_);
    atomicAdd(&stats[FD+tid], q_);
    if (cmx){
      float mx = fmaxf(fmaxf(smx[0][tid],smx[1][tid]), fmaxf(smx[2][tid],smx[3][tid]));
      float mn = fminf(fminf(smn[0][tid],smn[1][tid]), fminf(smn[2][tid],smn[3][tid]));
      atomicMax(&cmx[tid], enc(mx));
      atomicMin(&cmn[tid], enc(mn));
    }
  }
}

// -------- pool dot with fused BN-affine: p[v] = (a∘x + b) · wp --------
__global__ __launch_bounds__(256) void k_dotp(const float* __restrict__ X,
    const float* __restrict__ wp,
    const float* __restrict__ st, const float* __restrict__ g,
    const float* __restrict__ bt, float invn,
    float* __restrict__ p, int n){
  int tid = threadIdx.x;
  int v = blockIdx.x*4 + (tid >> 6), lane = tid & 63;
  if (v >= n) return;
  int c = lane * 2;
  float ma = st[c]*invn, mb = st[c+1]*invn;
  float va = st[FD+c]*invn - ma*ma, vb = st[FD+c+1]*invn - mb*mb;
  float ax = g[c]*rsqrtf(va + 1e-5f), ay = g[c+1]*rsqrtf(vb + 1e-5f);
  float bx = bt[c] - ma*ax,           by = bt[c+1] - mb*ay;
  float2 x = *(const float2*)(X + (size_t)v*FD + c);
  float2 w = *(const float2*)(wp + c);
  float s = (ax*x.x + bx)*w.x + (ay*x.y + by)*w.y;
  s += __shfl_xor(s,1); s += __shfl_xor(s,2); s += __shfl_xor(s,4);
  s += __shfl_xor(s,8); s += __shfl_xor(s,16); s += __shfl_xor(s,32);
  if (lane == 0) p[v] = s;
}

// -------- score + fused hi-digit histogram --------
__global__ void k_score(const float* __restrict__ p, const int* __restrict__ start,
    const int* __restrict__ degb, const int* __restrict__ csr,
    const float* __restrict__ bpool, int pi,
    float* __restrict__ score, unsigned* __restrict__ hist, int n){
  int v = blockIdx.x*256 + threadIdx.x;
  if (v >= n) return;
  int b = start[v], deg = degb[v];
  float s = p[v];
  for (int j = 0; j < deg; j++) s += p[csr[b+j]];
  float sc = tanhf(s / (float)(deg + 1) + bpool[pi]);
  score[v] = sc;
  atomicAdd(&hist[enc(sc) >> 16], 1u);
}

__global__ void k_hist_lo(const float* __restrict__ score, int n,
                          const unsigned* __restrict__ state, unsigned* __restrict__ hist){
  int v = blockIdx.x*256 + threadIdx.x;
  if (v >= n) return;
  unsigned key = enc(score[v]);
  if ((key >> 16) == state[5]) atomicAdd(&hist[key & 0xFFFFu], 1u);
}

__global__ __launch_bounds__(1024) void k_pick(const unsigned* __restrict__ hist,
                                               unsigned* __restrict__ state, int k, int pass){
  __shared__ unsigned wsum[16];
  int tid = threadIdx.x;
  unsigned want = (pass == 0) ? (unsigned)k : state[4];
  unsigned prevAbove = (pass == 0) ? 0u : state[1];
  int chunk = 1023 - tid;
  const unsigned* hbase = hist + chunk*64;
  unsigned csum = 0;
  #pragma unroll
  for (int j = 0; j < 64; j++) csum += hbase[j];
  unsigned val = csum;
  int lane = tid & 63, wid = tid >> 6;
  #pragma unroll
  for (int o = 1; o < 64; o <<= 1){ unsigned t = __shfl_up(val, o); if (lane >= o) val += t; }
  if (lane == 63) wsum[wid] = val;
  __syncthreads();
  if (tid < 16){
    unsigned v2 = wsum[tid];
    #pragma unroll
    for (int o = 1; o < 16; o <<= 1){ unsigned t = __shfl_up(v2, o); if (tid >= o) v2 += t; }
    wsum[tid] = v2;
  }
  __syncthreads();
  unsigned incl = val + ((wid > 0) ? wsum[wid-1] : 0u);
  unsigned excl = incl - csum;
  if (excl < want && incl >= want){
    unsigned cum = excl, above = 0; int bsel = 0;
    for (int j = 63; j >= 0; j--){
      unsigned cc = hbase[j];
      if (cum + cc >= want){ bsel = j; above = cum; break; }
      cum += cc;
    }
    unsigned bucket = (unsigned)(chunk*64 + bsel);
    if (pass == 0){
      state[5] = bucket;
      state[1] = prevAbove + above;
      state[4] = want - above;
    } else {
      unsigned T = (state[5] << 16) | bucket;
      unsigned totAbove = prevAbove + above;
      state[0] = T; state[1] = totAbove; state[2] = 0u; state[3] = totAbove;
    }
  }
}

__global__ void k_compact(const float* __restrict__ score, unsigned* __restrict__ state,
    int* __restrict__ rank, int* __restrict__ sel, int n, int k){
  int v = blockIdx.x*256 + threadIdx.x;
  if (v > n) return;
  if (v == n){ rank[n] = -1; return; }
  unsigned T = state[0];
  unsigned key = enc(score[v]);
  int slot = -1;
  if (key > T) slot = (int)atomicAdd(&state[2], 1u);
  else if (key == T){ unsigned t = atomicAdd(&state[3], 1u); if (t < (unsigned)k) slot = (int)t; }
  rank[v] = slot;
  if (slot >= 0) sel[slot] = v;
}

// -------- gather with fused BN-affine: out = (a∘x + b) * score --------
__global__ __launch_bounds__(256) void k_gather(const float* __restrict__ X,
    const int* __restrict__ sel, const float* __restrict__ score,
    const float* __restrict__ st, const float* __restrict__ g,
    const float* __restrict__ bt, float invn,
    float* __restrict__ XO, int k){
  int j = blockIdx.x*4 + (threadIdx.x >> 6), lane = threadIdx.x & 63;
  if (j >= k) return;
  int c = lane * 2;
  float ma = st[c]*invn, mb = st[c+1]*invn;
  float va = st[FD+c]*invn - ma*ma, vb = st[FD+c+1]*invn - mb*mb;
  float ax = g[c]*rsqrtf(va + 1e-5f), ay = g[c+1]*rsqrtf(vb + 1e-5f);
  float bx = bt[c] - ma*ax,           by = bt[c+1] - mb*ay;
  int u = sel[j];
  float sc = score[u];
  float2 t = *(const float2*)(X + (size_t)u*FD + c);
  t.x = (ax*t.x + bx)*sc; t.y = (ay*t.y + by)*sc;
  *(float2*)(XO + (size_t)j*FD + c) = t;
}

// -------- final: BN'd col-max readout (sign-aware from pre-BN max/min) + MLP --------
__global__ void k_final(const unsigned* __restrict__ cmx, const unsigned* __restrict__ cmn,
    const float* __restrict__ stats, const float* __restrict__ gamma,
    const float* __restrict__ beta,
    const float* __restrict__ W1, const float* __restrict__ b1,
    const float* __restrict__ W2, const float* __restrict__ b2,
    float* __restrict__ out){
  __shared__ float h[384];
  __shared__ float h1[50];
  int tid = threadIdx.x;
  if (tid < 384){
    int s = tid >> 7, c = tid & 127;
    const int liR[3] = {2,5,8};
    const float nsf[3] = {50000.f, 25000.f, 12500.f};
    int li = liR[s];
    const float* st = stats + (size_t)li*256;
    float invn = 1.f / nsf[s];
    float m = st[c]*invn, vv = st[FD+c]*invn - m*m;
    float a = gamma[(size_t)li*FD+c]*rsqrtf(vv + 1e-5f);
    float bb = beta[(size_t)li*FD+c] - m*a;
    float mx = dec(cmx[tid]), mn = dec(cmn[tid]);
    h[tid] = (a >= 0.f) ? (a*mx + bb) : (a*mn + bb);
  }
  __syncthreads();
  if (tid < 50){
    float acc = b1[tid];
    for (int i = 0; i < 384; i++) acc += h[i]*W1[i*50 + tid];
    h1[tid] = fmaxf(acc, 0.f);
  }
  __syncthreads();
  if (tid < 5){
    float acc = b2[tid];
    for (int i = 0; i < 50; i++) acc += h1[i]*W2[i*5 + tid];
    out[tid] = acc;
  }
}

extern "C" void kernel_launch(void* const* d_in, const int* in_sizes, int n_in,
                              void* d_out, int out_size, void* d_ws, size_t ws_size,
                              hipStream_t stream){
  (void)in_sizes; (void)n_in; (void)out_size; (void)ws_size;
  const float* x_in  = (const float*)d_in[0];
  const int*   ei    = (const int*)d_in[1];
  const float* Wc    = (const float*)d_in[2];
  const float* bc    = (const float*)d_in[3];
  const float* gamma = (const float*)d_in[4];
  const float* beta  = (const float*)d_in[5];
  const float* Wpool = (const float*)d_in[6];
  const float* bpool = (const float*)d_in[7];
  const float* W1    = (const float*)d_in[8];
  const float* b1    = (const float*)d_in[9];
  const float* W2    = (const float*)d_in[10];
  const float* b2    = (const float*)d_in[11];
  float* dout = (float*)d_out;

  char* base = (char*)d_ws; size_t o_ = 0;
  auto alloc = [&](size_t bytes)->void*{
    void* p = base + o_; o_ = (o_ + bytes + 255) & ~(size_t)255; return p;
  };
  float* B0   = (float*)alloc((size_t)NMAX*FD*4);
  float* B1   = (float*)alloc((size_t)NMAX*FD*4);
  int* eSrc   = (int*)alloc((size_t)EDG*4);
  int* eDst   = (int*)alloc((size_t)EDG*4);
  int* degb   = (int*)alloc((size_t)(NMAX+1)*4);   // deg counts + [n]=alloc counter
  int* startv = (int*)alloc((size_t)NMAX*4);
  int* cur    = (int*)alloc((size_t)NMAX*4);
  int* csr    = (int*)alloc((size_t)EDG*4);
  float* pbuf = (float*)alloc((size_t)NMAX*4);
  float* sbuf = (float*)alloc((size_t)NMAX*4);
  int* sel    = (int*)alloc((size_t)25000*4);
  int* rank   = (int*)alloc((size_t)(NMAX+1)*4);
  float* stats= (float*)alloc(9*256*4);
  unsigned* cmx = (unsigned*)alloc(384*4);
  unsigned* cmn = (unsigned*)alloc(384*4);
  unsigned* state= (unsigned*)alloc(64);
  unsigned* hist = (unsigned*)alloc(2*65536*4);

  const int ns[3]  = {50000, 25000, 12500};
  const int bnIdx[9] = {0,1,2,3,4,5,6,6,8};   // replicate the source bug (6,6,8)
  const int EB = (EDG + 255)/256;

  hipMemsetAsync(stats, 0, 9*256*4, stream);
  hipMemsetAsync(cmx, 0x00, 384*4, stream);
  hipMemsetAsync(cmn, 0xFF, 384*4, stream);

  const int* cs = ei;
  const int* cd = ei + EDG;

  for (int s = 0; s < 3; s++){
    int n = ns[s];
    float fin = 1.f/(float)n;
    float* X = (s == 1) ? B1 : B0;
    float* A = (s == 1) ? B0 : B1;

    hipMemsetAsync(degb, 0, (size_t)(n+1)*4, stream);   // counts + counter
    if (s == 0){
      k_count<<<dim3(EB), dim3(256), 0, stream>>>(cs, cd, degb, EDG);
    } else {
      k_remap_count<<<dim3(EB), dim3(256), 0, stream>>>(cs, cd, eSrc, eDst, rank, n, degb, EDG);
      cs = eSrc; cd = eDst;
    }
    k_offsets<<<dim3((n+255)/256), dim3(256), 0, stream>>>(degb, startv, cur, degb + n, n);
    k_fill<<<dim3(EB), dim3(256), 0, stream>>>(cs, cd, cur, csr, EDG);

    for (int i = 0; i < 3; i++){
      int li = s*3 + i;
      const float* xr = (s == 0 && i == 0) ? x_in : (const float*)X;
      const float* stPrev = (i == 0) ? (const float*)nullptr : stats + (size_t)(li-1)*256;
      int gb = (i == 0) ? 0 : bnIdx[li-1];
      bool rd = (i == 2);
      k_agg<<<dim3((n+3)/4), dim3(256), 0, stream>>>(xr, startv, degb, csr, A, n,
                                                     stPrev, gamma + (size_t)gb*FD, beta + (size_t)gb*FD, fin);
      k_gemm<<<dim3((n+FD-1)/FD), dim3(256), 0, stream>>>(A, Wc + (size_t)li*FD*FD, bc + li*FD, X,
                                                          stats + (size_t)li*256, n,
                                                          rd ? (cmx + s*FD) : (unsigned*)nullptr,
                                                          rd ? (cmn + s*FD) : (unsigned*)nullptr);
    }

    if (s < 2){
      int k = (s == 0) ? 25000 : 12500;
      int li2 = s*3 + 2;
      const float* st2 = stats + (size_t)li2*256;
      const float* g2 = gamma + (size_t)bnIdx[li2]*FD;
      const float* bt2 = beta + (size_t)bnIdx[li2]*FD;
      hipMemsetAsync(hist, 0, 2*65536*4, stream);
      k_dotp<<<dim3((n+3)/4), dim3(256), 0, stream>>>(X, Wpool + s*FD, st2, g2, bt2, fin, pbuf, n);
      k_score<<<dim3((n+255)/256), dim3(256), 0, stream>>>(pbuf, startv, degb, csr, bpool, s, sbuf, hist, n);
      k_pick<<<1, 1024, 0, stream>>>(hist, state, k, 0);
      k_hist_lo<<<dim3((n+255)/256), dim3(256), 0, stream>>>(sbuf, n, state, hist + 65536);
      k_pick<<<1, 1024, 0, stream>>>(hist + 65536, state, k, 1);
      k_compact<<<dim3((n+256)/256), dim3(256), 0, stream>>>(sbuf, state, rank, sel, n, k);
      k_gather<<<dim3((k+3)/4), dim3(256), 0, stream>>>(X, sel, sbuf, st2, g2, bt2, fin, A, k);
    }
  }
  k_final<<<1, 384, 0, stream>>>(cmx, cmn, stats, gamma, beta, W1, b1, W2, b2, dout);
}

// Round 9
// 928.746 us; speedup vs baseline: 1.4369x; 1.0362x over previous
//
#include <hip/hip_runtime.h>

constexpr int FD   = 128;
constexpr int NMAX = 50000;
constexpr int EDG  = 800000;

static __device__ __forceinline__ unsigned enc(float f){
  unsigned u = __float_as_uint(f);
  return (u & 0x80000000u) ? ~u : (u | 0x80000000u);
}
static __device__ __forceinline__ float dec(unsigned e){
  unsigned u = (e & 0x80000000u) ? (e ^ 0x80000000u) : ~e;
  return __uint_as_float(u);
}
static __device__ __forceinline__ unsigned short f2bf(float f){
  unsigned u = __float_as_uint(f);
  unsigned r = u + 0x7FFFu + ((u >> 16) & 1u);   // RNE
  return (unsigned short)(r >> 16);
}
static __device__ __forceinline__ float bf2f(unsigned short h){
  return __uint_as_float(((unsigned)h) << 16);
}

// ---------------- x_in -> bf16 mirror ----------------
__global__ __launch_bounds__(256) void k_cvt(const float* __restrict__ in,
                                             unsigned short* __restrict__ out, int n2){
  int i = blockIdx.x*256 + threadIdx.x;
  if (i >= n2) return;
  float2 v = ((const float2*)in)[i];
  ushort2 o; o.x = f2bf(v.x); o.y = f2bf(v.y);
  ((ushort2*)out)[i] = o;
}

// ---------------- CSR build ----------------
__global__ void k_count(const int* __restrict__ src, const int* __restrict__ dst,
                        int* __restrict__ deg, int E){
  int e = blockIdx.x*256 + threadIdx.x;
  if (e >= E) return;
  int s = src[e], d = dst[e];
  if (s != d) atomicAdd(&deg[d], 1);
}

__global__ void k_remap_count(const int* __restrict__ sIn, const int* __restrict__ dIn,
                              int* __restrict__ sOut, int* __restrict__ dOut,
                              const int* __restrict__ rank, int kNew,
                              int* __restrict__ deg, int E){
  int e = blockIdx.x*256 + threadIdx.x;
  if (e >= E) return;
  int s = sIn[e], d = dIn[e];
  int rs = rank[s], rd = rank[d];
  bool ok = (rs >= 0) && (rd >= 0);
  int os = ok ? rs : kNew, od = ok ? rd : kNew;
  sOut[e] = os; dOut[e] = od;
  if (os != od) atomicAdd(&deg[od], 1);
}

// ---- parallel offset allocation: per-block scan + one atomic block base ----
__global__ __launch_bounds__(256) void k_offsets(const int* __restrict__ deg,
    int* __restrict__ start, int* __restrict__ cur, int* __restrict__ total, int n){
  __shared__ int wsum[4];
  __shared__ int sbase;
  int tid = threadIdx.x, lane = tid & 63, wid = tid >> 6;
  int v = blockIdx.x*256 + tid;
  int x = (v < n) ? deg[v] : 0;
  int val = x;
  #pragma unroll
  for (int o = 1; o < 64; o <<= 1){ int t = __shfl_up(val, o); if (lane >= o) val += t; }
  if (lane == 63) wsum[wid] = val;
  __syncthreads();
  if (tid == 0){
    int t0 = wsum[0], t1 = wsum[1], t2 = wsum[2], t3 = wsum[3];
    sbase = atomicAdd(total, t0+t1+t2+t3);
    wsum[0] = 0; wsum[1] = t0; wsum[2] = t0+t1; wsum[3] = t0+t1+t2;
  }
  __syncthreads();
  int excl = (val - x) + wsum[wid] + sbase;
  if (v < n){ start[v] = excl; cur[v] = excl; }
}

__global__ void k_fill(const int* __restrict__ src, const int* __restrict__ dst,
                       int* __restrict__ cur, int* __restrict__ csr, int E){
  int e = blockIdx.x*256 + threadIdx.x;
  if (e >= E) return;
  int s = src[e], d = dst[e];
  if (s != d){ int pos = atomicAdd(&cur[d], 1); csr[pos] = s; }
}

// -------- aggregation over bf16 X, fp32 accum, fused BN-affine of prev layer --------
__global__ __launch_bounds__(256) void k_agg(const unsigned short* __restrict__ Xbf,
    const int* __restrict__ start, const int* __restrict__ degb,
    const int* __restrict__ csr,
    float* __restrict__ AGG, int n,
    const float* __restrict__ st, const float* __restrict__ g,
    const float* __restrict__ bt, float invn){
  int tid = threadIdx.x;
  int v = blockIdx.x*4 + (tid >> 6);
  if (v >= n) return;
  int lane = tid & 63;
  int c = lane * 2;
  float ax = 1.f, ay = 1.f, bx = 0.f, by = 0.f;
  if (st){
    float ma = st[c]*invn, mb = st[c+1]*invn;
    float va = st[FD+c]*invn - ma*ma, vb = st[FD+c+1]*invn - mb*mb;
    ax = g[c]*rsqrtf(va + 1e-5f);  ay = g[c+1]*rsqrtf(vb + 1e-5f);
    bx = bt[c] - ma*ax;            by = bt[c+1] - mb*ay;
  }
  int b = start[v];
  int deg = degb[v];
  ushort2 sv = *(const ushort2*)(Xbf + (size_t)v*FD + c);
  float sx = bf2f(sv.x), sy = bf2f(sv.y);
  int j = 0;
  while (j < deg){
    int cnt = deg - j; if (cnt > 64) cnt = 64;
    int myu = (j + lane < deg) ? csr[b + j + lane] : 0;
    int t = 0;
    for (; t + 8 <= cnt; t += 8){
      int u0 = __shfl(myu, t),   u1 = __shfl(myu, t+1);
      int u2 = __shfl(myu, t+2), u3 = __shfl(myu, t+3);
      int u4 = __shfl(myu, t+4), u5 = __shfl(myu, t+5);
      int u6 = __shfl(myu, t+6), u7 = __shfl(myu, t+7);
      ushort2 t0 = *(const ushort2*)(Xbf + (size_t)u0*FD + c);
      ushort2 t1 = *(const ushort2*)(Xbf + (size_t)u1*FD + c);
      ushort2 t2 = *(const ushort2*)(Xbf + (size_t)u2*FD + c);
      ushort2 t3 = *(const ushort2*)(Xbf + (size_t)u3*FD + c);
      ushort2 t4 = *(const ushort2*)(Xbf + (size_t)u4*FD + c);
      ushort2 t5 = *(const ushort2*)(Xbf + (size_t)u5*FD + c);
      ushort2 t6 = *(const ushort2*)(Xbf + (size_t)u6*FD + c);
      ushort2 t7 = *(const ushort2*)(Xbf + (size_t)u7*FD + c);
      sx += ((bf2f(t0.x)+bf2f(t1.x)) + (bf2f(t2.x)+bf2f(t3.x)))
          + ((bf2f(t4.x)+bf2f(t5.x)) + (bf2f(t6.x)+bf2f(t7.x)));
      sy += ((bf2f(t0.y)+bf2f(t1.y)) + (bf2f(t2.y)+bf2f(t3.y)))
          + ((bf2f(t4.y)+bf2f(t5.y)) + (bf2f(t6.y)+bf2f(t7.y)));
    }
    for (; t < cnt; t++){
      int u = __shfl(myu, t);
      ushort2 tt = *(const ushort2*)(Xbf + (size_t)u*FD + c);
      sx += bf2f(tt.x); sy += bf2f(tt.y);
    }
    j += cnt;
  }
  float inv = 1.f / (float)(deg + 1);
  float2 o;
  o.x = sx*inv*ax + bx;
  o.y = sy*inv*ay + by;
  *(float2*)(AGG + (size_t)v*FD + c) = o;
}

// ---- GEMM + bias + L2norm + ReLU + BN-stats; bf16 out always, fp32 out optional ----
__global__ __launch_bounds__(256,2) void k_gemm(const float* __restrict__ A,
    const float* __restrict__ W, const float* __restrict__ bias,
    float* __restrict__ Y, unsigned short* __restrict__ Ybf,
    float* __restrict__ stats, int n,
    unsigned* __restrict__ cmx, unsigned* __restrict__ cmn){
  __shared__ float sW[FD*FD];
  __shared__ float ss[4][FD];
  __shared__ float sq_[4][FD];
  __shared__ float smx[4][FD];
  __shared__ float smn[4][FD];
  int tid = threadIdx.x;
  {
    const float4* Wg = (const float4*)W; float4* Ws = (float4*)sW;
    for (int i = tid; i < FD*FD/4; i += 256) Ws[i] = Wg[i];
  }
  __syncthreads();
  int tc = tid & 15;
  int tr = tid >> 4;
  int rbase = blockIdx.x*FD + tr*8;
  float acc[8][8];
  #pragma unroll
  for (int i = 0; i < 8; i++)
    #pragma unroll
    for (int j = 0; j < 8; j++) acc[i][j] = 0.f;

  for (int k4 = 0; k4 < FD; k4 += 4){
    float4 a[8];
    #pragma unroll
    for (int i = 0; i < 8; i++){
      int r = rbase + i; if (r >= n) r = n - 1;
      a[i] = *(const float4*)(A + (size_t)r*FD + k4);
    }
    #pragma unroll
    for (int kk = 0; kk < 4; kk++){
      const float* wr = &sW[(k4+kk)*FD + tc*8];
      float4 w0 = *(const float4*)wr, w1 = *(const float4*)(wr+4);
      #pragma unroll
      for (int i = 0; i < 8; i++){
        float av = (kk==0) ? a[i].x : (kk==1) ? a[i].y : (kk==2) ? a[i].z : a[i].w;
        acc[i][0] += av*w0.x; acc[i][1] += av*w0.y; acc[i][2] += av*w0.z; acc[i][3] += av*w0.w;
        acc[i][4] += av*w1.x; acc[i][5] += av*w1.y; acc[i][6] += av*w1.z; acc[i][7] += av*w1.w;
      }
    }
  }
  float bx[8];
  {
    const float* bp = bias + tc*8;
    #pragma unroll
    for (int j = 0; j < 8; j++) bx[j] = bp[j];
  }
  float cs[8], cq[8], mxv[8], mnv[8];
  #pragma unroll
  for (int j = 0; j < 8; j++){ cs[j]=0.f; cq[j]=0.f; mxv[j]=-3.4e38f; mnv[j]=3.4e38f; }
  #pragma unroll
  for (int i = 0; i < 8; i++){
    int r = rbase + i;
    bool valid = (r < n);
    float y[8]; float sq = 0.f;
    #pragma unroll
    for (int j = 0; j < 8; j++){ y[j] = acc[i][j] + bx[j]; sq += y[j]*y[j]; }
    sq += __shfl_xor(sq,1); sq += __shfl_xor(sq,2); sq += __shfl_xor(sq,4); sq += __shfl_xor(sq,8);
    float nrm = sqrtf(sq);
    float sc = 1.f / fmaxf(nrm, 1e-12f);
    #pragma unroll
    for (int j = 0; j < 8; j++){ y[j] *= sc; y[j] = fmaxf(y[j], 0.f); }
    if (valid){
      if (Y){
        float* yo = Y + (size_t)r*FD + tc*8;
        *(float4*)yo     = make_float4(y[0],y[1],y[2],y[3]);
        *(float4*)(yo+4) = make_float4(y[4],y[5],y[6],y[7]);
      }
      unsigned pk0 = (unsigned)f2bf(y[0]) | ((unsigned)f2bf(y[1])<<16);
      unsigned pk1 = (unsigned)f2bf(y[2]) | ((unsigned)f2bf(y[3])<<16);
      unsigned pk2 = (unsigned)f2bf(y[4]) | ((unsigned)f2bf(y[5])<<16);
      unsigned pk3 = (unsigned)f2bf(y[6]) | ((unsigned)f2bf(y[7])<<16);
      *(uint4*)(Ybf + (size_t)r*FD + tc*8) = make_uint4(pk0,pk1,pk2,pk3);
      #pragma unroll
      for (int j = 0; j < 8; j++){
        cs[j] += y[j]; cq[j] += y[j]*y[j];
        mxv[j] = fmaxf(mxv[j], y[j]); mnv[j] = fminf(mnv[j], y[j]);
      }
    }
  }
  #pragma unroll
  for (int j = 0; j < 8; j++){
    cs[j] += __shfl_xor(cs[j],16); cs[j] += __shfl_xor(cs[j],32);
    cq[j] += __shfl_xor(cq[j],16); cq[j] += __shfl_xor(cq[j],32);
    mxv[j] = fmaxf(mxv[j], __shfl_xor(mxv[j],16)); mxv[j] = fmaxf(mxv[j], __shfl_xor(mxv[j],32));
    mnv[j] = fminf(mnv[j], __shfl_xor(mnv[j],16)); mnv[j] = fminf(mnv[j], __shfl_xor(mnv[j],32));
  }
  int wv = tid >> 6, lane = tid & 63;
  if (lane < 16){
    #pragma unroll
    for (int j = 0; j < 8; j++){
      ss[wv][tc*8+j] = cs[j]; sq_[wv][tc*8+j] = cq[j];
      smx[wv][tc*8+j] = mxv[j]; smn[wv][tc*8+j] = mnv[j];
    }
  }
  __syncthreads();
  if (tid < FD){
    float s_ = ss[0][tid]+ss[1][tid]+ss[2][tid]+ss[3][tid];
    float q_ = sq_[0][tid]+sq_[1][tid]+sq_[2][tid]+sq_[3][tid];
    atomicAdd(&stats[tid], s_);
    atomicAdd(&stats[FD+tid], q_);
    if (cmx){
      float mx = fmaxf(fmaxf(smx[0][tid],smx[1][tid]), fmaxf(smx[2][tid],smx[3][tid]));
      float mn = fminf(fminf(smn[0][tid],smn[1][tid]), fminf(smn[2][tid],smn[3][tid]));
      atomicMax(&cmx[tid], enc(mx));
      atomicMin(&cmn[tid], enc(mn));
    }
  }
}

// -------- pool dot with fused BN-affine + hist zeroing --------
__global__ __launch_bounds__(256) void k_dotp(const float* __restrict__ X,
    const float* __restrict__ wp,
    const float* __restrict__ st, const float* __restrict__ g,
    const float* __restrict__ bt, float invn,
    float* __restrict__ p, unsigned* __restrict__ hist, int n){
  int tid = threadIdx.x;
  if (blockIdx.x < 512) hist[blockIdx.x*256 + tid] = 0u;  // 512*256 = 2*65536
  int v = blockIdx.x*4 + (tid >> 6), lane = tid & 63;
  if (v >= n) return;
  int c = lane * 2;
  float ma = st[c]*invn, mb = st[c+1]*invn;
  float va = st[FD+c]*invn - ma*ma, vb = st[FD+c+1]*invn - mb*mb;
  float ax = g[c]*rsqrtf(va + 1e-5f), ay = g[c+1]*rsqrtf(vb + 1e-5f);
  float bx = bt[c] - ma*ax,           by = bt[c+1] - mb*ay;
  float2 x = *(const float2*)(X + (size_t)v*FD + c);
  float2 w = *(const float2*)(wp + c);
  float s = (ax*x.x + bx)*w.x + (ay*x.y + by)*w.y;
  s += __shfl_xor(s,1); s += __shfl_xor(s,2); s += __shfl_xor(s,4);
  s += __shfl_xor(s,8); s += __shfl_xor(s,16); s += __shfl_xor(s,32);
  if (lane == 0) p[v] = s;
}

// -------- wave-parallel score + fused hi-digit histogram --------
__global__ __launch_bounds__(256) void k_score(const float* __restrict__ p,
    const int* __restrict__ start, const int* __restrict__ degb,
    const int* __restrict__ csr, const float* __restrict__ bpool, int pi,
    float* __restrict__ score, unsigned* __restrict__ hist, int n){
  int tid = threadIdx.x, lane = tid & 63;
  int v = blockIdx.x*4 + (tid >> 6);
  if (v >= n) return;
  int b = start[v], deg = degb[v];
  float s = 0.f;
  for (int j = lane; j < deg; j += 64) s += p[csr[b+j]];
  s += __shfl_xor(s,1); s += __shfl_xor(s,2); s += __shfl_xor(s,4);
  s += __shfl_xor(s,8); s += __shfl_xor(s,16); s += __shfl_xor(s,32);
  if (lane == 0){
    s += p[v];
    float sc = tanhf(s / (float)(deg + 1) + bpool[pi]);
    score[v] = sc;
    atomicAdd(&hist[enc(sc) >> 16], 1u);
  }
}

__global__ void k_hist_lo(const float* __restrict__ score, int n,
                          const unsigned* __restrict__ state, unsigned* __restrict__ hist){
  int v = blockIdx.x*256 + threadIdx.x;
  if (v >= n) return;
  unsigned key = enc(score[v]);
  if ((key >> 16) == state[5]) atomicAdd(&hist[key & 0xFFFFu], 1u);
}

__global__ __launch_bounds__(1024) void k_pick(const unsigned* __restrict__ hist,
                                               unsigned* __restrict__ state, int k, int pass){
  __shared__ unsigned wsum[16];
  int tid = threadIdx.x;
  unsigned want = (pass == 0) ? (unsigned)k : state[4];
  unsigned prevAbove = (pass == 0) ? 0u : state[1];
  int chunk = 1023 - tid;
  const unsigned* hbase = hist + chunk*64;
  unsigned csum = 0;
  #pragma unroll
  for (int j = 0; j < 64; j++) csum += hbase[j];
  unsigned val = csum;
  int lane = tid & 63, wid = tid >> 6;
  #pragma unroll
  for (int o = 1; o < 64; o <<= 1){ unsigned t = __shfl_up(val, o); if (lane >= o) val += t; }
  if (lane == 63) wsum[wid] = val;
  __syncthreads();
  if (tid < 16){
    unsigned v2 = wsum[tid];
    #pragma unroll
    for (int o = 1; o < 16; o <<= 1){ unsigned t = __shfl_up(v2, o); if (tid >= o) v2 += t; }
    wsum[tid] = v2;
  }
  __syncthreads();
  unsigned incl = val + ((wid > 0) ? wsum[wid-1] : 0u);
  unsigned excl = incl - csum;
  if (excl < want && incl >= want){
    unsigned cum = excl, above = 0; int bsel = 0;
    for (int j = 63; j >= 0; j--){
      unsigned cc = hbase[j];
      if (cum + cc >= want){ bsel = j; above = cum; break; }
      cum += cc;
    }
    unsigned bucket = (unsigned)(chunk*64 + bsel);
    if (pass == 0){
      state[5] = bucket;
      state[1] = prevAbove + above;
      state[4] = want - above;
    } else {
      unsigned T = (state[5] << 16) | bucket;
      unsigned totAbove = prevAbove + above;
      state[0] = T; state[1] = totAbove; state[2] = 0u; state[3] = totAbove;
    }
  }
}

__global__ void k_compact(const float* __restrict__ score, unsigned* __restrict__ state,
    int* __restrict__ rank, int* __restrict__ sel, int n, int k){
  int v = blockIdx.x*256 + threadIdx.x;
  if (v > n) return;
  if (v == n){ rank[n] = -1; return; }
  unsigned T = state[0];
  unsigned key = enc(score[v]);
  int slot = -1;
  if (key > T) slot = (int)atomicAdd(&state[2], 1u);
  else if (key == T){ unsigned t = atomicAdd(&state[3], 1u); if (t < (unsigned)k) slot = (int)t; }
  rank[v] = slot;
  if (slot >= 0) sel[slot] = v;
}

// -------- gather: out_bf16 = (a∘x + b) * score --------
__global__ __launch_bounds__(256) void k_gather(const float* __restrict__ X,
    const int* __restrict__ sel, const float* __restrict__ score,
    const float* __restrict__ st, const float* __restrict__ g,
    const float* __restrict__ bt, float invn,
    unsigned short* __restrict__ XObf, int k){
  int j = blockIdx.x*4 + (threadIdx.x >> 6), lane = threadIdx.x & 63;
  if (j >= k) return;
  int c = lane * 2;
  float ma = st[c]*invn, mb = st[c+1]*invn;
  float va = st[FD+c]*invn - ma*ma, vb = st[FD+c+1]*invn - mb*mb;
  float ax = g[c]*rsqrtf(va + 1e-5f), ay = g[c+1]*rsqrtf(vb + 1e-5f);
  float bx = bt[c] - ma*ax,           by = bt[c+1] - mb*ay;
  int u = sel[j];
  float sc = score[u];
  float2 t = *(const float2*)(X + (size_t)u*FD + c);
  ushort2 o;
  o.x = f2bf((ax*t.x + bx)*sc);
  o.y = f2bf((ay*t.y + by)*sc);
  *(ushort2*)(XObf + (size_t)j*FD + c) = o;
}

// -------- final: BN'd col-max readout (sign-aware from pre-BN max/min) + MLP --------
__global__ void k_final(const unsigned* __restrict__ cmx, const unsigned* __restrict__ cmn,
    const float* __restrict__ stats, const float* __restrict__ gamma,
    const float* __restrict__ beta,
    const float* __restrict__ W1, const float* __restrict__ b1,
    const float* __restrict__ W2, const float* __restrict__ b2,
    float* __restrict__ out){
  __shared__ float h[384];
  __shared__ float h1[50];
  int tid = threadIdx.x;
  if (tid < 384){
    int s = tid >> 7, c = tid & 127;
    const int liR[3] = {2,5,8};
    const float nsf[3] = {50000.f, 25000.f, 12500.f};
    int li = liR[s];
    const float* st = stats + (size_t)li*256;
    float invn = 1.f / nsf[s];
    float m = st[c]*invn, vv = st[FD+c]*invn - m*m;
    float a = gamma[(size_t)li*FD+c]*rsqrtf(vv + 1e-5f);
    float bb = beta[(size_t)li*FD+c] - m*a;
    float mx = dec(cmx[tid]), mn = dec(cmn[tid]);
    h[tid] = (a >= 0.f) ? (a*mx + bb) : (a*mn + bb);
  }
  __syncthreads();
  if (tid < 50){
    float acc = b1[tid];
    for (int i = 0; i < 384; i++) acc += h[i]*W1[i*50 + tid];
    h1[tid] = fmaxf(acc, 0.f);
  }
  __syncthreads();
  if (tid < 5){
    float acc = b2[tid];
    for (int i = 0; i < 50; i++) acc += h1[i]*W2[i*5 + tid];
    out[tid] = acc;
  }
}

extern "C" void kernel_launch(void* const* d_in, const int* in_sizes, int n_in,
                              void* d_out, int out_size, void* d_ws, size_t ws_size,
                              hipStream_t stream){
  (void)in_sizes; (void)n_in; (void)out_size; (void)ws_size;
  const float* x_in  = (const float*)d_in[0];
  const int*   ei    = (const int*)d_in[1];
  const float* Wc    = (const float*)d_in[2];
  const float* bc    = (const float*)d_in[3];
  const float* gamma = (const float*)d_in[4];
  const float* beta  = (const float*)d_in[5];
  const float* Wpool = (const float*)d_in[6];
  const float* bpool = (const float*)d_in[7];
  const float* W1    = (const float*)d_in[8];
  const float* b1    = (const float*)d_in[9];
  const float* W2    = (const float*)d_in[10];
  const float* b2    = (const float*)d_in[11];
  float* dout = (float*)d_out;

  char* base = (char*)d_ws; size_t o_ = 0;
  auto alloc = [&](size_t bytes)->void*{
    void* p = base + o_; o_ = (o_ + bytes + 255) & ~(size_t)255; return p;
  };
  float* B0   = (float*)alloc((size_t)NMAX*FD*4);
  float* B1   = (float*)alloc((size_t)NMAX*FD*4);
  unsigned short* B0bf = (unsigned short*)alloc((size_t)NMAX*FD*2);
  unsigned short* B1bf = (unsigned short*)alloc((size_t)NMAX*FD*2);
  int* eSrc   = (int*)alloc((size_t)EDG*4);
  int* eDst   = (int*)alloc((size_t)EDG*4);
  int* degb   = (int*)alloc((size_t)(NMAX+1)*4);   // deg counts + [n]=alloc counter
  int* startv = (int*)alloc((size_t)NMAX*4);
  int* cur    = (int*)alloc((size_t)NMAX*4);
  int* csr    = (int*)alloc((size_t)EDG*4);
  float* pbuf = (float*)alloc((size_t)NMAX*4);
  float* sbuf = (float*)alloc((size_t)NMAX*4);
  int* sel    = (int*)alloc((size_t)25000*4);
  int* rank   = (int*)alloc((size_t)(NMAX+1)*4);
  float* stats= (float*)alloc(9*256*4);
  unsigned* cmx = (unsigned*)alloc(384*4);
  unsigned* cmn = (unsigned*)alloc(384*4);
  unsigned* state= (unsigned*)alloc(64);
  unsigned* hist = (unsigned*)alloc(2*65536*4);

  const int ns[3]  = {50000, 25000, 12500};
  const int bnIdx[9] = {0,1,2,3,4,5,6,6,8};   // replicate the source bug (6,6,8)
  const int EB = (EDG + 255)/256;

  hipMemsetAsync(stats, 0, 9*256*4, stream);
  hipMemsetAsync(cmx, 0x00, 384*4, stream);
  hipMemsetAsync(cmn, 0xFF, 384*4, stream);

  // x_in -> bf16 (B0bf is stage-0's Xbf; overwritten by layer-0 gemm afterwards)
  k_cvt<<<dim3((NMAX*FD/2 + 255)/256), dim3(256), 0, stream>>>(x_in, B0bf, NMAX*FD/2);

  const int* cs = ei;
  const int* cd = ei + EDG;

  for (int s = 0; s < 3; s++){
    int n = ns[s];
    float fin = 1.f/(float)n;
    float* X = (s == 1) ? B1 : B0;
    unsigned short* Xbf = (s == 1) ? B1bf : B0bf;
    float* A = (s == 1) ? B0 : B1;
    unsigned short* Abf = (s == 1) ? B0bf : B1bf;

    hipMemsetAsync(degb, 0, (size_t)(n+1)*4, stream);
    if (s == 0){
      k_count<<<dim3(EB), dim3(256), 0, stream>>>(cs, cd, degb, EDG);
    } else {
      k_remap_count<<<dim3(EB), dim3(256), 0, stream>>>(cs, cd, eSrc, eDst, rank, n, degb, EDG);
      cs = eSrc; cd = eDst;
    }
    k_offsets<<<dim3((n+255)/256), dim3(256), 0, stream>>>(degb, startv, cur, degb + n, n);
    k_fill<<<dim3(EB), dim3(256), 0, stream>>>(cs, cd, cur, csr, EDG);

    for (int i = 0; i < 3; i++){
      int li = s*3 + i;
      const float* stPrev = (i == 0) ? (const float*)nullptr : stats + (size_t)(li-1)*256;
      int gb = (i == 0) ? 0 : bnIdx[li-1];
      bool rd = (i == 2);
      bool writeF = (i == 2) && (s < 2);   // fp32 X needed only by dotp/gather
      k_agg<<<dim3((n+3)/4), dim3(256), 0, stream>>>(Xbf, startv, degb, csr, A, n,
                                                     stPrev, gamma + (size_t)gb*FD, beta + (size_t)gb*FD, fin);
      k_gemm<<<dim3((n+FD-1)/FD), dim3(256), 0, stream>>>(A, Wc + (size_t)li*FD*FD, bc + li*FD,
                                                          writeF ? X : (float*)nullptr, Xbf,
                                                          stats + (size_t)li*256, n,
                                                          rd ? (cmx + s*FD) : (unsigned*)nullptr,
                                                          rd ? (cmn + s*FD) : (unsigned*)nullptr);
    }

    if (s < 2){
      int k = (s == 0) ? 25000 : 12500;
      int li2 = s*3 + 2;
      const float* st2 = stats + (size_t)li2*256;
      const float* g2 = gamma + (size_t)bnIdx[li2]*FD;
      const float* bt2 = beta + (size_t)bnIdx[li2]*FD;
      k_dotp<<<dim3((n+3)/4), dim3(256), 0, stream>>>(X, Wpool + s*FD, st2, g2, bt2, fin, pbuf, hist, n);
      k_score<<<dim3((n+3)/4), dim3(256), 0, stream>>>(pbuf, startv, degb, csr, bpool, s, sbuf, hist, n);
      k_pick<<<1, 1024, 0, stream>>>(hist, state, k, 0);
      k_hist_lo<<<dim3((n+255)/256), dim3(256), 0, stream>>>(sbuf, n, state, hist + 65536);
      k_pick<<<1, 1024, 0, stream>>>(hist + 65536, state, k, 1);
      k_compact<<<dim3((n+256)/256), dim3(256), 0, stream>>>(sbuf, state, rank, sel, n, k);
      k_gather<<<dim3((k+3)/4), dim3(256), 0, stream>>>(X, sel, sbuf, st2, g2, bt2, fin, Abf, k);
    }
  }
  k_final<<<1, 384, 0, stream>>>(cmx, cmn, stats, gamma, beta, W1, b1, W2, b2, dout);
}